// Round 2
// baseline (3462.275 us; speedup 1.0000x reference)
//
#include <hip/hip_runtime.h>
#include <hip/hip_bf16.h>
#include <math.h>

#define EPSV 1e-4f

// ---------------- weight normalization ----------------
__global__ void wnorm_kernel(const float* __restrict__ w, float* __restrict__ wn,
                             int L, float invsqrtL, const float* __restrict__ gain_ptr) {
    int r = blockIdx.x;
    const float* row = w + (size_t)r * L;
    float ss = 0.f;
    for (int i = threadIdx.x; i < L; i += 256) { float v = row[i]; ss += v * v; }
#pragma unroll
    for (int m = 32; m >= 1; m >>= 1) ss += __shfl_xor(ss, m);
    __shared__ float sdata[4];
    int wid = threadIdx.x >> 6, lane = threadIdx.x & 63;
    if (lane == 0) sdata[wid] = ss;
    __syncthreads();
    float tot = sdata[0] + sdata[1] + sdata[2] + sdata[3];
    float g = gain_ptr ? gain_ptr[0] : 1.0f;
    float s = g * invsqrtL / (EPSV + sqrtf(tot) * invsqrtL);
    float* outr = wn + (size_t)r * L;
    for (int i = threadIdx.x; i < L; i += 256) outr[i] = row[i] * s;
}

// ---------------- pixel norm + mp_silu ----------------
__global__ void pixnorm_kernel(const float* __restrict__ x, float* __restrict__ xn,
                               float* __restrict__ a0) {
    int blk = blockIdx.x;
    int n = blk >> 4;
    int pg = threadIdx.x & 63;
    int cg = threadIdx.x >> 6;
    int p = ((blk & 15) << 6) + pg;
    const float* xb = x + (size_t)n * 262144 + p;
    float ss = 0.f;
#pragma unroll 4
    for (int i = 0; i < 64; i++) {
        float v = xb[(size_t)(cg * 64 + i) << 10];
        ss += v * v;
    }
    __shared__ float red[4][64];
    red[cg][pg] = ss;
    __syncthreads();
    float tot = red[0][pg] + red[1][pg] + red[2][pg] + red[3][pg];
    float inv = 1.0f / (EPSV + sqrtf(tot) * 0.0625f);
    for (int i = 0; i < 64; i++) {
        size_t idx = (size_t)n * 262144 + ((size_t)(cg * 64 + i) << 10) + p;
        float v = x[idx] * inv;
        xn[idx] = v;
        float sg = 1.0f / (1.0f + __expf(-v));
        a0[idx] = v * sg * (1.0f / 0.596f);
    }
}

// ---------------- c = emb @ w_emb_n^T + 1 ----------------
__global__ void emb_kernel(const float* __restrict__ emb, const float* __restrict__ wn,
                           float* __restrict__ cvec) {
    int n = blockIdx.x;
    __shared__ float es[768];
    for (int i = threadIdx.x; i < 768; i += 256) es[i] = emb[n * 768 + i];
    __syncthreads();
    const float* wr = wn + (size_t)threadIdx.x * 768;
    float acc = 0.f;
    for (int k = 0; k < 768; k++) acc += es[k] * wr[k];
    cvec[n * 256 + threadIdx.x] = acc + 1.0f;
}

// ---------------- 3x3 conv, pad 1, H=W=32 ----------------
__global__ __launch_bounds__(256) void conv3_kernel(const float* __restrict__ x,
        const float* __restrict__ wn, float* __restrict__ y, int Cin, int Cout) {
    const int OCB = 8;
    int oc0 = blockIdx.x * OCB;
    int n = blockIdx.y;
    int pw = threadIdx.x & 31;
    int ph0 = (threadIdx.x >> 5) << 2;
    __shared__ float xs[34 * 34];
    __shared__ float ws[OCB * 9];
    float acc[OCB][4];
#pragma unroll
    for (int o = 0; o < OCB; o++)
#pragma unroll
        for (int j = 0; j < 4; j++) acc[o][j] = 0.f;
    const float* xb = x + (size_t)n * Cin * 1024;
    for (int ic = 0; ic < Cin; ic++) {
        __syncthreads();
        for (int idx = threadIdx.x; idx < 34 * 34; idx += 256) {
            int r = idx / 34;
            int cc = idx - r * 34;
            int ih = r - 1, iw = cc - 1;
            float v = 0.f;
            if ((unsigned)ih < 32u && (unsigned)iw < 32u)
                v = xb[(size_t)ic * 1024 + ih * 32 + iw];
            xs[idx] = v;
        }
        if (threadIdx.x < OCB * 9) {
            int o = threadIdx.x / 9, k = threadIdx.x - o * 9;
            ws[threadIdx.x] = wn[((size_t)(oc0 + o) * Cin + ic) * 9 + k];
        }
        __syncthreads();
        float xv[6][3];
#pragma unroll
        for (int r6 = 0; r6 < 6; r6++)
#pragma unroll
            for (int c3 = 0; c3 < 3; c3++)
                xv[r6][c3] = xs[(ph0 + r6) * 34 + pw + c3];
#pragma unroll
        for (int o = 0; o < OCB; o++) {
            float w0 = ws[o*9+0], w1 = ws[o*9+1], w2 = ws[o*9+2];
            float w3 = ws[o*9+3], w4 = ws[o*9+4], w5 = ws[o*9+5];
            float w6 = ws[o*9+6], w7 = ws[o*9+7], w8 = ws[o*9+8];
#pragma unroll
            for (int j = 0; j < 4; j++) {
                acc[o][j] += w0*xv[j][0] + w1*xv[j][1] + w2*xv[j][2]
                           + w3*xv[j+1][0] + w4*xv[j+1][1] + w5*xv[j+1][2]
                           + w6*xv[j+2][0] + w7*xv[j+2][1] + w8*xv[j+2][2];
            }
        }
    }
#pragma unroll
    for (int o = 0; o < OCB; o++)
#pragma unroll
        for (int j = 0; j < 4; j++)
            y[((size_t)n * Cout + oc0 + o) * 1024 + (ph0 + j) * 32 + pw] = acc[o][j];
}

// ---------------- 1x1 conv (templated output type) ----------------
template <typename OutT>
__global__ __launch_bounds__(256) void conv1_kernel(const float* __restrict__ x,
        const float* __restrict__ wn, OutT* __restrict__ y, int Cin, int Cout) {
    const int OCB = 16;
    int oc0 = blockIdx.x * OCB;
    int n = blockIdx.y;
    int pw = threadIdx.x & 31;
    int ph0 = (threadIdx.x >> 5) << 2;
    __shared__ float xs[1024];
    __shared__ float ws[OCB];
    float acc[OCB][4];
#pragma unroll
    for (int o = 0; o < OCB; o++)
#pragma unroll
        for (int j = 0; j < 4; j++) acc[o][j] = 0.f;
    const float* xb = x + (size_t)n * Cin * 1024;
    for (int ic = 0; ic < Cin; ic++) {
        __syncthreads();
#pragma unroll
        for (int k = 0; k < 4; k++)
            xs[threadIdx.x + k * 256] = xb[(size_t)ic * 1024 + threadIdx.x + k * 256];
        if (threadIdx.x < OCB)
            ws[threadIdx.x] = wn[(size_t)(oc0 + threadIdx.x) * Cin + ic];
        __syncthreads();
        float xv[4];
#pragma unroll
        for (int j = 0; j < 4; j++) xv[j] = xs[(ph0 + j) * 32 + pw];
#pragma unroll
        for (int o = 0; o < OCB; o++) {
            float wv = ws[o];
#pragma unroll
            for (int j = 0; j < 4; j++) acc[o][j] += wv * xv[j];
        }
    }
#pragma unroll
    for (int o = 0; o < OCB; o++)
#pragma unroll
        for (int j = 0; j < 4; j++)
            y[((size_t)n * Cout + oc0 + o) * 1024 + (ph0 + j) * 32 + pw] = (OutT)acc[o][j];
}

// ---------------- y2 = mp_silu(y * c) ----------------
__global__ void silumul_kernel(const float* __restrict__ y, const float* __restrict__ cvec,
                               float* __restrict__ outp) {
    int i = blockIdx.x * 256 + threadIdx.x;
    int n = i >> 18;
    int ch = (i >> 10) & 255;
    float v = y[i] * cvec[n * 256 + ch];
    float sg = 1.0f / (1.0f + __expf(-v));
    outp[i] = v * sg * (1.0f / 0.596f);
}

// ---------------- mp_sum (+ optional clip) ----------------
__global__ void mpsum_kernel(const float* __restrict__ a, const float* __restrict__ b,
                             float* __restrict__ outp, float wa, float wb, int doclip) {
    int i = blockIdx.x * 256 + threadIdx.x;
    float v = a[i] * wa + b[i] * wb;
    if (doclip) v = fminf(fmaxf(v, -256.f), 256.f);
    outp[i] = v;
}

// ---------------- qkv per-head l2 normalize (in place, bf16) ----------------
__global__ void qkvnorm_kernel(__hip_bfloat16* __restrict__ qkv) {
    int g = blockIdx.x;                 // n*12 + h*3 + tt
    int n = g / 12;
    int r = g - n * 12;
    int h = r / 3;
    int tt = r - h * 3;
    int s = blockIdx.y * 256 + threadIdx.x;
    __hip_bfloat16* base = qkv + ((size_t)n * 768 + h * 192 + tt) * 1024 + s;
    float vals[64];
    float ss = 0.f;
#pragma unroll 4
    for (int c = 0; c < 64; c++) {
        float v = __bfloat162float(base[(size_t)c * 3072]);
        vals[c] = v;
        ss += v * v;
    }
    float inv = 1.0f / (EPSV + sqrtf(ss) * 0.125f);     // alpha = 1/8
#pragma unroll 4
    for (int c = 0; c < 64; c++)
        base[(size_t)c * 3072] = __float2bfloat16(vals[c] * inv);
}

// ---------------- attention (bf16 qkv in, fp32 out) ----------------
__global__ __launch_bounds__(256) void attn_kernel(const __hip_bfloat16* __restrict__ qkv,
                                                   float* __restrict__ outp) {
    int qt = blockIdx.x, h = blockIdx.y, n = blockIdx.z;
    const __hip_bfloat16* base = qkv + ((size_t)n * 768 + h * 192) * 1024;
    __shared__ __align__(16) float Qs[64][68];   // [c][q]
    __shared__ __align__(16) float Ks[64][68];   // [c][k]
    __shared__ __align__(16) float Vt[64][68];   // [k][c]
    __shared__ __align__(16) float Pt[64][68];   // [k][q]
    int t = threadIdx.x;
    int lq = t & 63, cg = t >> 6;
    int g4 = t & 15;
    int qg = t >> 4;
#pragma unroll
    for (int i = 0; i < 16; i++) {
        int c = cg * 16 + i;
        Qs[c][lq] = __bfloat162float(base[(size_t)(c * 3) * 1024 + qt * 64 + lq]);
    }
    float o_acc[4][4];
    float m_run[4], l_run[4];
#pragma unroll
    for (int j = 0; j < 4; j++) {
        m_run[j] = -1e30f; l_run[j] = 0.f;
#pragma unroll
        for (int i = 0; i < 4; i++) o_acc[j][i] = 0.f;
    }
    __syncthreads();
    for (int kt = 0; kt < 16; kt++) {
#pragma unroll
        for (int i = 0; i < 16; i++) {
            int c = cg * 16 + i;
            Ks[c][lq] = __bfloat162float(base[(size_t)(c * 3 + 1) * 1024 + kt * 64 + lq]);
            Vt[lq][c] = __bfloat162float(base[(size_t)(c * 3 + 2) * 1024 + kt * 64 + lq]);
        }
        __syncthreads();
        float sc[4][4];
#pragma unroll
        for (int j = 0; j < 4; j++)
#pragma unroll
            for (int i = 0; i < 4; i++) sc[j][i] = 0.f;
        for (int c = 0; c < 64; c++) {
            float4 kvv = *(const float4*)&Ks[c][g4 * 4];
            float4 qvv = *(const float4*)&Qs[c][qg * 4];
            float kv[4] = {kvv.x, kvv.y, kvv.z, kvv.w};
            float qv[4] = {qvv.x, qvv.y, qvv.z, qvv.w};
#pragma unroll
            for (int j = 0; j < 4; j++)
#pragma unroll
                for (int i = 0; i < 4; i++) sc[j][i] += qv[j] * kv[i];
        }
#pragma unroll
        for (int j = 0; j < 4; j++) {
#pragma unroll
            for (int i = 0; i < 4; i++) sc[j][i] *= 0.125f;
            float tm = fmaxf(fmaxf(sc[j][0], sc[j][1]), fmaxf(sc[j][2], sc[j][3]));
            tm = fmaxf(tm, __shfl_xor(tm, 1));
            tm = fmaxf(tm, __shfl_xor(tm, 2));
            tm = fmaxf(tm, __shfl_xor(tm, 4));
            tm = fmaxf(tm, __shfl_xor(tm, 8));
            float mnew = fmaxf(m_run[j], tm);
            float f = __expf(m_run[j] - mnew);
            m_run[j] = mnew;
            float rs = 0.f;
#pragma unroll
            for (int i = 0; i < 4; i++) { sc[j][i] = __expf(sc[j][i] - mnew); rs += sc[j][i]; }
            rs += __shfl_xor(rs, 1);
            rs += __shfl_xor(rs, 2);
            rs += __shfl_xor(rs, 4);
            rs += __shfl_xor(rs, 8);
            l_run[j] = l_run[j] * f + rs;
#pragma unroll
            for (int i = 0; i < 4; i++) o_acc[j][i] *= f;
        }
#pragma unroll
        for (int i = 0; i < 4; i++) {
            float4 pv = make_float4(sc[0][i], sc[1][i], sc[2][i], sc[3][i]);
            *(float4*)&Pt[g4 * 4 + i][qg * 4] = pv;
        }
        __syncthreads();
        for (int kk = 0; kk < 64; kk++) {
            float4 vvv = *(const float4*)&Vt[kk][g4 * 4];
            float4 pvv = *(const float4*)&Pt[kk][qg * 4];
            float vv[4] = {vvv.x, vvv.y, vvv.z, vvv.w};
            float pv[4] = {pvv.x, pvv.y, pvv.z, pvv.w};
#pragma unroll
            for (int j = 0; j < 4; j++)
#pragma unroll
                for (int i = 0; i < 4; i++) o_acc[j][i] += pv[j] * vv[i];
        }
        __syncthreads();
    }
    size_t obase = ((size_t)n * 256 + h * 64) * 1024 + qt * 64 + qg * 4;
#pragma unroll
    for (int i = 0; i < 4; i++) {
        float4 ov = make_float4(o_acc[0][i] / l_run[0], o_acc[1][i] / l_run[1],
                                o_acc[2][i] / l_run[2], o_acc[3][i] / l_run[3]);
        *(float4*)&outp[obase + (size_t)(g4 * 4 + i) * 1024] = ov;
    }
}

extern "C" void kernel_launch(void* const* d_in, const int* in_sizes, int n_in,
                              void* d_out, int out_size, void* d_ws, size_t ws_size,
                              hipStream_t stream) {
    (void)in_sizes; (void)n_in; (void)out_size; (void)ws_size;
    const float* x       = (const float*)d_in[0];
    const float* emb     = (const float*)d_in[1];
    const float* w_res0  = (const float*)d_in[2];
    const float* w_emb   = (const float*)d_in[3];
    const float* w_res1  = (const float*)d_in[4];
    const float* w_qkv   = (const float*)d_in[5];
    const float* w_proj  = (const float*)d_in[6];
    const float* emb_gain= (const float*)d_in[7];
    float* out = (float*)d_out;

    // Compact workspace layout (floats). Total need: 2.5*T + 1,646,592 floats
    // = 90,472,448 bytes (~86.3 MB). d_out doubles as conv ping-pong / attn-out.
    const size_t T = 8388608;              // 32*256*1024
    float* ws   = (float*)d_ws;
    float* X    = ws;                      // [0, T)      x_n -> x1 (live till end)
    float* A    = ws + T;                  // [T, 2T)     silu / y2 / proj-out
    float* Bb   = out;                     // d_out as scratch: conv out / attn out
    __hip_bfloat16* QKVh = (__hip_bfloat16*)(ws + T);   // [T, 2.5T): 3T bf16 elems
    float* WGT  = ws + (T * 5) / 2;        // 2.5T
    float* W0N  = WGT;                     // 589824
    float* W1N  = W0N + 589824;            // 589824
    float* WQN  = W1N + 589824;            // 196608
    float* WPN  = WQN + 196608;            // 65536
    float* WEN  = WPN + 65536;             // 196608
    float* CC   = WEN + 196608;            // 8192

    const float wa = 0.91914503f;          // 0.7 / sqrt(0.58)
    const float wb = 0.39392215f;          // 0.3 / sqrt(0.58)

    wnorm_kernel<<<256, 256, 0, stream>>>(w_res0, W0N, 2304, 1.0f / 48.0f, nullptr);
    wnorm_kernel<<<256, 256, 0, stream>>>(w_res1, W1N, 2304, 1.0f / 48.0f, nullptr);
    wnorm_kernel<<<256, 256, 0, stream>>>(w_emb,  WEN, 768, 0.036084392f, emb_gain);
    wnorm_kernel<<<768, 256, 0, stream>>>(w_qkv,  WQN, 256, 0.0625f, nullptr);
    wnorm_kernel<<<256, 256, 0, stream>>>(w_proj, WPN, 256, 0.0625f, nullptr);

    pixnorm_kernel<<<512, 256, 0, stream>>>(x, X, A);                 // X = x_n, A = mp_silu(x_n)
    emb_kernel<<<32, 256, 0, stream>>>(emb, WEN, CC);                 // CC = c
    conv3_kernel<<<dim3(32, 32), 256, 0, stream>>>(A, W0N, Bb, 256, 256);     // Bb = y
    silumul_kernel<<<32768, 256, 0, stream>>>(Bb, CC, A);             // A = mp_silu(y*c)
    conv3_kernel<<<dim3(32, 32), 256, 0, stream>>>(A, W1N, Bb, 256, 256);     // Bb = y3
    mpsum_kernel<<<32768, 256, 0, stream>>>(X, Bb, X, wa, wb, 0);     // X = x1
    conv1_kernel<__hip_bfloat16><<<dim3(48, 32), 256, 0, stream>>>(X, WQN, QKVh, 256, 768);
    qkvnorm_kernel<<<dim3(384, 4), 256, 0, stream>>>(QKVh);           // normalize in place
    attn_kernel<<<dim3(16, 4, 32), 256, 0, stream>>>(QKVh, Bb);       // Bb = attn out (fp32)
    conv1_kernel<float><<<dim3(16, 32), 256, 0, stream>>>(Bb, WPN, A, 256, 256);  // A = proj
    mpsum_kernel<<<32768, 256, 0, stream>>>(X, A, out, wa, wb, 1);    // out = clip(mp_sum)
}

// Round 3
// 838.569 us; speedup vs baseline: 4.1288x; 4.1288x over previous
//
#include <hip/hip_runtime.h>
#include <hip/hip_bf16.h>
#include <math.h>

#define EPSV 1e-4f
#define WA 0.91914503f          // 0.7 / sqrt(0.58)
#define WB 0.39392215f          // 0.3 / sqrt(0.58)
#define INV596 1.6778523f       // 1/0.596

typedef __bf16 bf16x8 __attribute__((ext_vector_type(8)));
typedef short  s16x8  __attribute__((ext_vector_type(8)));
typedef float  f32x4  __attribute__((ext_vector_type(4)));

__device__ inline bf16x8 bzero8() { s16x8 z = 0; return __builtin_bit_cast(bf16x8, z); }

__device__ inline void store_bf4(__hip_bfloat16* p, float a, float b, float c, float d) {
    __hip_bfloat16 t[4];
    t[0] = __float2bfloat16(a); t[1] = __float2bfloat16(b);
    t[2] = __float2bfloat16(c); t[3] = __float2bfloat16(d);
    *(short4*)p = *(short4*)t;
}

// ---------------- weight norm: 3x3 conv -> bf16 [tap][oc][ic] ----------------
__global__ void wnorm3k(const float* __restrict__ w, __hip_bfloat16* __restrict__ wb) {
    int oc = blockIdx.x;
    const float* row = w + (size_t)oc * 2304;
    float ss = 0.f;
    for (int i = threadIdx.x; i < 2304; i += 256) { float v = row[i]; ss += v * v; }
#pragma unroll
    for (int m = 32; m >= 1; m >>= 1) ss += __shfl_xor(ss, m);
    __shared__ float sdata[4];
    int wid = threadIdx.x >> 6, lane = threadIdx.x & 63;
    if (lane == 0) sdata[wid] = ss;
    __syncthreads();
    float tot = sdata[0] + sdata[1] + sdata[2] + sdata[3];
    float s = (1.0f / 48.0f) / (EPSV + sqrtf(tot) * (1.0f / 48.0f));
    for (int i = threadIdx.x; i < 2304; i += 256) {
        int ic = i / 9, tap = i - ic * 9;
        wb[((size_t)tap * 256 + oc) * 256 + ic] = __float2bfloat16(row[i] * s);
    }
}

// ---------------- weight norm: 1x1 conv -> bf16 [oc][ic] ----------------
__global__ void wnorm1k(const float* __restrict__ w, __hip_bfloat16* __restrict__ wb) {
    int oc = blockIdx.x;
    const float* row = w + (size_t)oc * 256;
    float v0 = row[threadIdx.x];
    float ss = v0 * v0;
#pragma unroll
    for (int m = 32; m >= 1; m >>= 1) ss += __shfl_xor(ss, m);
    __shared__ float sdata[4];
    int wid = threadIdx.x >> 6, lane = threadIdx.x & 63;
    if (lane == 0) sdata[wid] = ss;
    __syncthreads();
    float tot = sdata[0] + sdata[1] + sdata[2] + sdata[3];
    float s = 0.0625f / (EPSV + sqrtf(tot) * 0.0625f);
    wb[(size_t)oc * 256 + threadIdx.x] = __float2bfloat16(v0 * s);
}

// ---------------- weight norm fp32 (emb) ----------------
__global__ void wnorm_kernel(const float* __restrict__ w, float* __restrict__ wn,
                             int L, float invsqrtL, const float* __restrict__ gain_ptr) {
    int r = blockIdx.x;
    const float* row = w + (size_t)r * L;
    float ss = 0.f;
    for (int i = threadIdx.x; i < L; i += 256) { float v = row[i]; ss += v * v; }
#pragma unroll
    for (int m = 32; m >= 1; m >>= 1) ss += __shfl_xor(ss, m);
    __shared__ float sdata[4];
    int wid = threadIdx.x >> 6, lane = threadIdx.x & 63;
    if (lane == 0) sdata[wid] = ss;
    __syncthreads();
    float tot = sdata[0] + sdata[1] + sdata[2] + sdata[3];
    float g = gain_ptr ? gain_ptr[0] : 1.0f;
    float s = g * invsqrtL / (EPSV + sqrtf(tot) * invsqrtL);
    float* outr = wn + (size_t)r * L;
    for (int i = threadIdx.x; i < L; i += 256) outr[i] = row[i] * s;
}

// ---------------- pixel norm: NCHW fp32 in -> NHWC fp32 xn + NHWC bf16 silu ----------------
__global__ void pixnorm2(const float* __restrict__ x, float* __restrict__ Xn,
                         __hip_bfloat16* __restrict__ Ah) {
    int n = blockIdx.y;
    int sp = blockIdx.x * 256 + threadIdx.x;
    const float* xb = x + (size_t)n * 262144 + sp;
    float ss = 0.f;
#pragma unroll 8
    for (int c = 0; c < 256; c++) { float v = xb[(size_t)c << 10]; ss += v * v; }
    float inv = 1.0f / (EPSV + sqrtf(ss) * 0.0625f);
    float* xo = Xn + ((size_t)n * 1024 + sp) * 256;
    __hip_bfloat16* ao = Ah + ((size_t)n * 1024 + sp) * 256;
#pragma unroll 8
    for (int c = 0; c < 256; c++) {
        float v = xb[(size_t)c << 10] * inv;
        xo[c] = v;
        float s = v / (1.0f + __expf(-v)) * INV596;
        ao[c] = __float2bfloat16(s);
    }
}

// ---------------- c = emb @ w_emb_n^T + 1 ----------------
__global__ void emb_kernel(const float* __restrict__ emb, const float* __restrict__ wn,
                           float* __restrict__ cvec) {
    int n = blockIdx.x;
    __shared__ float es[768];
    for (int i = threadIdx.x; i < 768; i += 256) es[i] = emb[n * 768 + i];
    __syncthreads();
    const float* wr = wn + (size_t)threadIdx.x * 768;
    float acc = 0.f;
    for (int k = 0; k < 768; k++) acc += es[k] * wr[k];
    cvec[n * 256 + threadIdx.x] = acc + 1.0f;
}

// ---------------- MFMA implicit-GEMM conv ----------------
// KS: 3 or 1. ORI 1: D[oc][sp]; ORI 2: D[sp][oc].
// EPI 1: silu(acc*c) -> bf16 NHWC | 2: mp_sum(xres,acc) -> f32+bf16 NHWC (in-place xres ok)
// EPI 3: bf16 NCHW (needs ORI2)   | 4: f32 NHWC
// input xin: NHWC bf16 [n][1024][Cin]; weights wb: [TAPS][Cout][Cin] bf16
template<int KS, int ORI, int EPI>
__global__ __launch_bounds__(256) void convmfma(
        const __hip_bfloat16* __restrict__ xin,
        const __hip_bfloat16* __restrict__ wb,
        __hip_bfloat16* __restrict__ out_h,
        float* __restrict__ out_f,
        const float* __restrict__ xres,
        __hip_bfloat16* __restrict__ out_h2,
        const float* __restrict__ cvec,
        int Cin, int Cout) {
    constexpr int TAPS = KS * KS;
    constexpr int RRD = 8 + KS - 1;
    constexpr int CCD = 32 + KS - 1;
    constexpr int HLO = KS / 2;
    __shared__ __align__(16) __hip_bfloat16 Xl[RRD][CCD][40];
    __shared__ __align__(16) __hip_bfloat16 Wl[TAPS][64][40];

    int oc0 = blockIdx.x * 64;
    int spblk = blockIdx.y;            // 0..3, 256 spatial each (8 rows)
    int n = blockIdx.z;
    int r0 = spblk * 8;
    int lane = threadIdx.x & 63, wv = threadIdx.x >> 6;
    int l15 = lane & 15, kb = (lane >> 4) * 8;

    // zero the always-zero column halo (cols -1 and 32) once
    if (KS == 3) {
        if (threadIdx.x < RRD * 2 * 4) {
            int rr = threadIdx.x >> 3;
            int side = (threadIdx.x >> 2) & 1;
            int slot = threadIdx.x & 3;
            *(bf16x8*)&Xl[rr][side ? (CCD - 1) : 0][slot * 8] = bzero8();
        }
    }

    f32x4 acc[4][4];
    const f32x4 z4 = {0.f, 0.f, 0.f, 0.f};
#pragma unroll
    for (int a = 0; a < 4; a++)
#pragma unroll
        for (int b = 0; b < 4; b++) acc[a][b] = z4;

    int nch = Cin >> 5;
    for (int ch = 0; ch < nch; ++ch) {
        __syncthreads();
        // stage input tile (interior cols), bf16x8 per slot
        for (int f = threadIdx.x; f < RRD * 128; f += 256) {
            int rr = f >> 7, rem = f & 127;
            int cc = rem >> 2, slot = rem & 3;
            int gr = r0 + rr - HLO;
            bf16x8 v = bzero8();
            if ((unsigned)gr < 32u)
                v = *(const bf16x8*)&xin[((size_t)n * 1024 + gr * 32 + cc) * Cin + ch * 32 + slot * 8];
            *(bf16x8*)&Xl[rr][cc + HLO][slot * 8] = v;
        }
        // stage weights chunk
        for (int f = threadIdx.x; f < TAPS * 256; f += 256) {
            int tap = f >> 8, rem = f & 255;
            int oc = rem >> 2, slot = rem & 3;
            bf16x8 v = *(const bf16x8*)&wb[((size_t)tap * Cout + oc0 + oc) * Cin + ch * 32 + slot * 8];
            *(bf16x8*)&Wl[tap][oc][slot * 8] = v;
        }
        __syncthreads();
#pragma unroll
        for (int tap = 0; tap < TAPS; ++tap) {
            int dy = tap / KS, dx = tap % KS;
            bf16x8 af[4], bfv[4];
#pragma unroll
            for (int of = 0; of < 4; of++)
                af[of] = *(const bf16x8*)&Wl[tap][of * 16 + l15][kb];
#pragma unroll
            for (int sf = 0; sf < 4; sf++) {
                int rr = 2 * wv + (sf >> 1) + dy;
                int cc2 = (sf & 1) * 16 + l15 + dx;
                bfv[sf] = *(const bf16x8*)&Xl[rr][cc2][kb];
            }
#pragma unroll
            for (int of = 0; of < 4; of++)
#pragma unroll
                for (int sf = 0; sf < 4; sf++) {
                    if (ORI == 1)
                        acc[of][sf] = __builtin_amdgcn_mfma_f32_16x16x32_bf16(af[of], bfv[sf], acc[of][sf], 0, 0, 0);
                    else
                        acc[of][sf] = __builtin_amdgcn_mfma_f32_16x16x32_bf16(bfv[sf], af[of], acc[of][sf], 0, 0, 0);
                }
        }
    }

    // epilogue
#pragma unroll
    for (int of = 0; of < 4; of++)
#pragma unroll
        for (int sf = 0; sf < 4; sf++) {
            if (ORI == 1) {
                // D[oc][sp]: col=lane&15 -> sp, row=(lane>>4)*4+r -> oc
                int row_l = 2 * wv + (sf >> 1);
                int col = (sf & 1) * 16 + l15;
                int sp = spblk * 256 + row_l * 32 + col;
                int ocb = oc0 + of * 16 + (lane >> 4) * 4;
                size_t a = ((size_t)n * 1024 + sp) * Cout + ocb;
                if (EPI == 1) {
                    float vv[4];
#pragma unroll
                    for (int r = 0; r < 4; r++) {
                        float t = acc[of][sf][r] * cvec[n * 256 + ocb + r];
                        vv[r] = t / (1.0f + __expf(-t)) * INV596;
                    }
                    store_bf4(&out_h[a], vv[0], vv[1], vv[2], vv[3]);
                } else if (EPI == 2) {
                    float4 xr = *(const float4*)&xres[a];
                    float v0 = WA * xr.x + WB * acc[of][sf][0];
                    float v1 = WA * xr.y + WB * acc[of][sf][1];
                    float v2 = WA * xr.z + WB * acc[of][sf][2];
                    float v3 = WA * xr.w + WB * acc[of][sf][3];
                    *(float4*)&out_f[a] = make_float4(v0, v1, v2, v3);
                    store_bf4(&out_h2[a], v0, v1, v2, v3);
                } else { // EPI 4
                    *(float4*)&out_f[a] = make_float4(acc[of][sf][0], acc[of][sf][1],
                                                      acc[of][sf][2], acc[of][sf][3]);
                }
            } else {
                // ORI2, EPI3: D[sp][oc]: col=lane&15 -> oc, row -> sp. NCHW bf16 out.
                int oc = oc0 + of * 16 + l15;
                int sp = spblk * 256 + (2 * wv + (sf >> 1)) * 32 + (sf & 1) * 16 + (lane >> 4) * 4;
                store_bf4(&out_h[((size_t)n * Cout + oc) * 1024 + sp],
                          acc[of][sf][0], acc[of][sf][1], acc[of][sf][2], acc[of][sf][3]);
            }
        }
}

// ---------------- qkv per-head l2 normalize (in place, NCHW bf16) ----------------
__global__ void qkvnorm_kernel(__hip_bfloat16* __restrict__ qkv) {
    int g = blockIdx.x;                 // n*12 + h*3 + tt
    int n = g / 12;
    int r = g - n * 12;
    int h = r / 3;
    int tt = r - h * 3;
    int s = blockIdx.y * 256 + threadIdx.x;
    __hip_bfloat16* base = qkv + ((size_t)n * 768 + h * 192 + tt) * 1024 + s;
    float vals[64];
    float ss = 0.f;
#pragma unroll
    for (int c = 0; c < 64; c++) {
        float v = __bfloat162float(base[(size_t)c * 3072]);
        vals[c] = v;
        ss += v * v;
    }
    float inv = 1.0f / (EPSV + sqrtf(ss) * 0.125f);
#pragma unroll
    for (int c = 0; c < 64; c++)
        base[(size_t)c * 3072] = __float2bfloat16(vals[c] * inv);
}

// ---------------- attention (NCHW bf16 qkv -> NHWC bf16 out) ----------------
__global__ __launch_bounds__(256) void attn_kernel(const __hip_bfloat16* __restrict__ qkv,
                                                   __hip_bfloat16* __restrict__ outp) {
    int qt = blockIdx.x, h = blockIdx.y, n = blockIdx.z;
    const __hip_bfloat16* base = qkv + ((size_t)n * 768 + h * 192) * 1024;
    __shared__ __align__(16) float Qs[64][68];
    __shared__ __align__(16) float Ks[64][68];
    __shared__ __align__(16) float Vt[64][68];
    __shared__ __align__(16) float Pt[64][68];
    int t = threadIdx.x;
    int lq = t & 63, cg = t >> 6;
    int g4 = t & 15;
    int qg = t >> 4;
#pragma unroll
    for (int i = 0; i < 16; i++) {
        int c = cg * 16 + i;
        Qs[c][lq] = __bfloat162float(base[(size_t)(c * 3) * 1024 + qt * 64 + lq]);
    }
    float o_acc[4][4];
    float m_run[4], l_run[4];
#pragma unroll
    for (int j = 0; j < 4; j++) {
        m_run[j] = -1e30f; l_run[j] = 0.f;
#pragma unroll
        for (int i = 0; i < 4; i++) o_acc[j][i] = 0.f;
    }
    __syncthreads();
    for (int kt = 0; kt < 16; kt++) {
#pragma unroll
        for (int i = 0; i < 16; i++) {
            int c = cg * 16 + i;
            Ks[c][lq] = __bfloat162float(base[(size_t)(c * 3 + 1) * 1024 + kt * 64 + lq]);
            Vt[lq][c] = __bfloat162float(base[(size_t)(c * 3 + 2) * 1024 + kt * 64 + lq]);
        }
        __syncthreads();
        float sc[4][4];
#pragma unroll
        for (int j = 0; j < 4; j++)
#pragma unroll
            for (int i = 0; i < 4; i++) sc[j][i] = 0.f;
        for (int c = 0; c < 64; c++) {
            float4 kvv = *(const float4*)&Ks[c][g4 * 4];
            float4 qvv = *(const float4*)&Qs[c][qg * 4];
            float kv[4] = {kvv.x, kvv.y, kvv.z, kvv.w};
            float qv[4] = {qvv.x, qvv.y, qvv.z, qvv.w};
#pragma unroll
            for (int j = 0; j < 4; j++)
#pragma unroll
                for (int i = 0; i < 4; i++) sc[j][i] += qv[j] * kv[i];
        }
#pragma unroll
        for (int j = 0; j < 4; j++) {
#pragma unroll
            for (int i = 0; i < 4; i++) sc[j][i] *= 0.125f;
            float tm = fmaxf(fmaxf(sc[j][0], sc[j][1]), fmaxf(sc[j][2], sc[j][3]));
            tm = fmaxf(tm, __shfl_xor(tm, 1));
            tm = fmaxf(tm, __shfl_xor(tm, 2));
            tm = fmaxf(tm, __shfl_xor(tm, 4));
            tm = fmaxf(tm, __shfl_xor(tm, 8));
            float mnew = fmaxf(m_run[j], tm);
            float f = __expf(m_run[j] - mnew);
            m_run[j] = mnew;
            float rs = 0.f;
#pragma unroll
            for (int i = 0; i < 4; i++) { sc[j][i] = __expf(sc[j][i] - mnew); rs += sc[j][i]; }
            rs += __shfl_xor(rs, 1);
            rs += __shfl_xor(rs, 2);
            rs += __shfl_xor(rs, 4);
            rs += __shfl_xor(rs, 8);
            l_run[j] = l_run[j] * f + rs;
#pragma unroll
            for (int i = 0; i < 4; i++) o_acc[j][i] *= f;
        }
#pragma unroll
        for (int i = 0; i < 4; i++) {
            float4 pv = make_float4(sc[0][i], sc[1][i], sc[2][i], sc[3][i]);
            *(float4*)&Pt[g4 * 4 + i][qg * 4] = pv;
        }
        __syncthreads();
        for (int kk = 0; kk < 64; kk++) {
            float4 vvv = *(const float4*)&Vt[kk][g4 * 4];
            float4 pvv = *(const float4*)&Pt[kk][qg * 4];
            float vv[4] = {vvv.x, vvv.y, vvv.z, vvv.w};
            float pv[4] = {pvv.x, pvv.y, pvv.z, pvv.w};
#pragma unroll
            for (int j = 0; j < 4; j++)
#pragma unroll
                for (int i = 0; i < 4; i++) o_acc[j][i] += pv[j] * vv[i];
        }
        __syncthreads();
    }
    // NHWC bf16 store: out[((n*1024 + q)*256) + h*64 + c]
#pragma unroll
    for (int j = 0; j < 4; j++) {
        size_t a = ((size_t)n * 1024 + qt * 64 + qg * 4 + j) * 256 + h * 64 + g4 * 4;
        float il = 1.0f / l_run[j];
        store_bf4(&outp[a], o_acc[j][0] * il, o_acc[j][1] * il, o_acc[j][2] * il, o_acc[j][3] * il);
    }
}

// ---------------- final: out = clip(mp_sum(X, P)), NHWC->NCHW transpose ----------------
__global__ __launch_bounds__(256) void final_kernel(const float* __restrict__ X,
        const float* __restrict__ P, float* __restrict__ outp) {
    int oc0 = blockIdx.x * 64, sp0 = blockIdx.y * 64, n = blockIdx.z;
    __shared__ float Ts[64][68];
    for (int q = threadIdx.x; q < 1024; q += 256) {
        int sp_l = q >> 4, qc = q & 15;
        size_t a = ((size_t)n * 1024 + sp0 + sp_l) * 256 + oc0 + qc * 4;
        float4 xv = *(const float4*)&X[a];
        float4 pv = *(const float4*)&P[a];
        float4 v;
        v.x = fminf(fmaxf(WA * xv.x + WB * pv.x, -256.f), 256.f);
        v.y = fminf(fmaxf(WA * xv.y + WB * pv.y, -256.f), 256.f);
        v.z = fminf(fmaxf(WA * xv.z + WB * pv.z, -256.f), 256.f);
        v.w = fminf(fmaxf(WA * xv.w + WB * pv.w, -256.f), 256.f);
        *(float4*)&Ts[sp_l][qc * 4] = v;
    }
    __syncthreads();
    for (int q = threadIdx.x; q < 1024; q += 256) {
        int oc_l = q >> 4, sq = q & 15;
        float4 v = make_float4(Ts[sq * 4 + 0][oc_l], Ts[sq * 4 + 1][oc_l],
                               Ts[sq * 4 + 2][oc_l], Ts[sq * 4 + 3][oc_l]);
        *(float4*)&outp[((size_t)n * 256 + oc0 + oc_l) * 1024 + sp0 + sq * 4] = v;
    }
}

extern "C" void kernel_launch(void* const* d_in, const int* in_sizes, int n_in,
                              void* d_out, int out_size, void* d_ws, size_t ws_size,
                              hipStream_t stream) {
    (void)in_sizes; (void)n_in; (void)out_size; (void)ws_size;
    const float* x        = (const float*)d_in[0];
    const float* emb      = (const float*)d_in[1];
    const float* w_res0   = (const float*)d_in[2];
    const float* w_emb    = (const float*)d_in[3];
    const float* w_res1   = (const float*)d_in[4];
    const float* w_qkv    = (const float*)d_in[5];
    const float* w_proj   = (const float*)d_in[6];
    const float* emb_gain = (const float*)d_in[7];
    float* out = (float*)d_out;

    // layout (~99.6 MB):
    // [0,32M)  X fp32 NHWC (x_n -> x1, in-place)
    // [32,48M) A1h bf16: silu(x_n) -> x1h -> attn-out
    // [48,96M) QKV NCHW bf16 (A2h = first 16M doubles as silu(y*c)); P fp32 = [64,96M)
    // [96M..)  weights
    const size_t MB = 1048576;
    char* wsb = (char*)d_ws;
    float* X            = (float*)wsb;
    __hip_bfloat16* A1h = (__hip_bfloat16*)(wsb + 32 * MB);
    __hip_bfloat16* A2h = (__hip_bfloat16*)(wsb + 48 * MB);
    __hip_bfloat16* QKV = A2h;
    float* P            = (float*)(wsb + 64 * MB);
    char* wp = wsb + 96 * MB;
    __hip_bfloat16* W0B = (__hip_bfloat16*)wp;              wp += 9 * 256 * 256 * 2;
    __hip_bfloat16* W1B = (__hip_bfloat16*)wp;              wp += 9 * 256 * 256 * 2;
    __hip_bfloat16* WQB = (__hip_bfloat16*)wp;              wp += 768 * 256 * 2;
    __hip_bfloat16* WPB = (__hip_bfloat16*)wp;              wp += 256 * 256 * 2;
    float* WEN          = (float*)wp;                       wp += 256 * 768 * 4;
    float* CC           = (float*)wp;

    wnorm3k<<<256, 256, 0, stream>>>(w_res0, W0B);
    wnorm3k<<<256, 256, 0, stream>>>(w_res1, W1B);
    wnorm1k<<<768, 256, 0, stream>>>(w_qkv, WQB);
    wnorm1k<<<256, 256, 0, stream>>>(w_proj, WPB);
    wnorm_kernel<<<256, 256, 0, stream>>>(w_emb, WEN, 768, 0.036084392f, emb_gain);

    pixnorm2<<<dim3(4, 32), 256, 0, stream>>>(x, X, A1h);
    emb_kernel<<<32, 256, 0, stream>>>(emb, WEN, CC);

    // conv3 #1: silu(x_n) -> silu(y*c) [bf16 NHWC]
    convmfma<3, 1, 1><<<dim3(4, 4, 32), 256, 0, stream>>>(A1h, W0B, A2h, nullptr, nullptr, nullptr, CC, 256, 256);
    // conv3 #2: -> x1 = mp_sum(x_n, y3) [fp32 + bf16 NHWC]
    convmfma<3, 1, 2><<<dim3(4, 4, 32), 256, 0, stream>>>(A2h, W1B, nullptr, X, X, A1h, nullptr, 256, 256);
    // qkv 1x1: x1h -> QKV [NCHW bf16]
    convmfma<1, 2, 3><<<dim3(12, 4, 32), 256, 0, stream>>>(A1h, WQB, QKV, nullptr, nullptr, nullptr, nullptr, 256, 768);
    qkvnorm_kernel<<<dim3(384, 4), 256, 0, stream>>>(QKV);
    attn_kernel<<<dim3(16, 4, 32), 256, 0, stream>>>(QKV, A1h);   // A1h = attn out bf16 NHWC
    // proj 1x1: -> P fp32 NHWC
    convmfma<1, 1, 4><<<dim3(4, 4, 32), 256, 0, stream>>>(A1h, WPB, nullptr, P, nullptr, nullptr, nullptr, 256, 256);
    final_kernel<<<dim3(4, 16, 32), 256, 0, stream>>>(X, P, out);
}

// Round 4
// 376.675 us; speedup vs baseline: 9.1917x; 2.2262x over previous
//
#include <hip/hip_runtime.h>
#include <hip/hip_bf16.h>
#include <math.h>

#define EPSV 1e-4f
#define WA 0.91914503f          // 0.7 / sqrt(0.58)
#define WB 0.39392215f          // 0.3 / sqrt(0.58)
#define INV596 1.6778523f       // 1/0.596

typedef __bf16 bf16x8 __attribute__((ext_vector_type(8)));
typedef short  s16x8  __attribute__((ext_vector_type(8)));
typedef float  f32x4  __attribute__((ext_vector_type(4)));

__device__ inline bf16x8 bzero8() { s16x8 z = 0; return __builtin_bit_cast(bf16x8, z); }

__device__ inline void store_bf4(__hip_bfloat16* p, float a, float b, float c, float d) {
    __hip_bfloat16 t[4];
    t[0] = __float2bfloat16(a); t[1] = __float2bfloat16(b);
    t[2] = __float2bfloat16(c); t[3] = __float2bfloat16(d);
    *(short4*)p = *(short4*)t;
}

__device__ inline float bfbits2f(short u) {
    return __uint_as_float(((unsigned)(unsigned short)u) << 16);
}

// ---------------- weight norm: 3x3 conv -> bf16 [tap][oc][ic] ----------------
__global__ void wnorm3k(const float* __restrict__ w, __hip_bfloat16* __restrict__ wb) {
    int oc = blockIdx.x;
    const float* row = w + (size_t)oc * 2304;
    float ss = 0.f;
    for (int i = threadIdx.x; i < 2304; i += 256) { float v = row[i]; ss += v * v; }
#pragma unroll
    for (int m = 32; m >= 1; m >>= 1) ss += __shfl_xor(ss, m);
    __shared__ float sdata[4];
    int wid = threadIdx.x >> 6, lane = threadIdx.x & 63;
    if (lane == 0) sdata[wid] = ss;
    __syncthreads();
    float tot = sdata[0] + sdata[1] + sdata[2] + sdata[3];
    float s = (1.0f / 48.0f) / (EPSV + sqrtf(tot) * (1.0f / 48.0f));
    for (int i = threadIdx.x; i < 2304; i += 256) {
        int ic = i / 9, tap = i - ic * 9;
        wb[((size_t)tap * 256 + oc) * 256 + ic] = __float2bfloat16(row[i] * s);
    }
}

// ---------------- weight norm: 1x1 conv -> bf16 [oc][ic] (plain) ----------------
__global__ void wnorm1k(const float* __restrict__ w, __hip_bfloat16* __restrict__ wb) {
    int oc = blockIdx.x;
    const float* row = w + (size_t)oc * 256;
    float v0 = row[threadIdx.x];
    float ss = v0 * v0;
#pragma unroll
    for (int m = 32; m >= 1; m >>= 1) ss += __shfl_xor(ss, m);
    __shared__ float sdata[4];
    int wid = threadIdx.x >> 6, lane = threadIdx.x & 63;
    if (lane == 0) sdata[wid] = ss;
    __syncthreads();
    float tot = sdata[0] + sdata[1] + sdata[2] + sdata[3];
    float s = 0.0625f / (EPSV + sqrtf(tot) * 0.0625f);
    wb[(size_t)oc * 256 + threadIdx.x] = __float2bfloat16(v0 * s);
}

// ---------------- weight norm: qkv 1x1, rows permuted (h,c,t)->(t,h,c) ----------------
__global__ void wnorm1kq(const float* __restrict__ w, __hip_bfloat16* __restrict__ wb) {
    int oc = blockIdx.x;                    // original row: h*192 + c*3 + t
    const float* row = w + (size_t)oc * 256;
    float v0 = row[threadIdx.x];
    float ss = v0 * v0;
#pragma unroll
    for (int m = 32; m >= 1; m >>= 1) ss += __shfl_xor(ss, m);
    __shared__ float sdata[4];
    int wid = threadIdx.x >> 6, lane = threadIdx.x & 63;
    if (lane == 0) sdata[wid] = ss;
    __syncthreads();
    float tot = sdata[0] + sdata[1] + sdata[2] + sdata[3];
    float s = 0.0625f / (EPSV + sqrtf(tot) * 0.0625f);
    int h = oc / 192, rem = oc - h * 192;
    int c = rem / 3, t = rem - c * 3;
    int newoc = t * 256 + h * 64 + c;
    wb[(size_t)newoc * 256 + threadIdx.x] = __float2bfloat16(v0 * s);
}

// ---------------- weight norm fp32 (emb) ----------------
__global__ void wnorm_kernel(const float* __restrict__ w, float* __restrict__ wn,
                             int L, float invsqrtL, const float* __restrict__ gain_ptr) {
    int r = blockIdx.x;
    const float* row = w + (size_t)r * L;
    float ss = 0.f;
    for (int i = threadIdx.x; i < L; i += 256) { float v = row[i]; ss += v * v; }
#pragma unroll
    for (int m = 32; m >= 1; m >>= 1) ss += __shfl_xor(ss, m);
    __shared__ float sdata[4];
    int wid = threadIdx.x >> 6, lane = threadIdx.x & 63;
    if (lane == 0) sdata[wid] = ss;
    __syncthreads();
    float tot = sdata[0] + sdata[1] + sdata[2] + sdata[3];
    float g = gain_ptr ? gain_ptr[0] : 1.0f;
    float s = g * invsqrtL / (EPSV + sqrtf(tot) * invsqrtL);
    float* outr = wn + (size_t)r * L;
    for (int i = threadIdx.x; i < L; i += 256) outr[i] = row[i] * s;
}

// ---------------- pixel norm: NCHW fp32 in -> NHWC fp32 xn + NHWC bf16 silu ----------------
__global__ void pixnorm2(const float* __restrict__ x, float* __restrict__ Xn,
                         __hip_bfloat16* __restrict__ Ah) {
    int n = blockIdx.y;
    int sp = blockIdx.x * 256 + threadIdx.x;
    const float* xb = x + (size_t)n * 262144 + sp;
    float ss = 0.f;
#pragma unroll 8
    for (int c = 0; c < 256; c++) { float v = xb[(size_t)c << 10]; ss += v * v; }
    float inv = 1.0f / (EPSV + sqrtf(ss) * 0.0625f);
    float* xo = Xn + ((size_t)n * 1024 + sp) * 256;
    __hip_bfloat16* ao = Ah + ((size_t)n * 1024 + sp) * 256;
#pragma unroll 8
    for (int c = 0; c < 256; c++) {
        float v = xb[(size_t)c << 10] * inv;
        xo[c] = v;
        float s = v / (1.0f + __expf(-v)) * INV596;
        ao[c] = __float2bfloat16(s);
    }
}

// ---------------- c = emb @ w_emb_n^T + 1 ----------------
__global__ void emb_kernel(const float* __restrict__ emb, const float* __restrict__ wn,
                           float* __restrict__ cvec) {
    int n = blockIdx.x;
    __shared__ float es[768];
    for (int i = threadIdx.x; i < 768; i += 256) es[i] = emb[n * 768 + i];
    __syncthreads();
    const float* wr = wn + (size_t)threadIdx.x * 768;
    float acc = 0.f;
    for (int k = 0; k < 768; k++) acc += es[k] * wr[k];
    cvec[n * 256 + threadIdx.x] = acc + 1.0f;
}

// ---------------- MFMA implicit-GEMM conv ----------------
// KS: 3 or 1. ORI 1: D[oc][sp]; ORI 2: D[sp][oc].
// EPI 1: silu(acc*c) -> bf16 NHWC       | EPI 2: mp_sum(xres,acc) -> f32+bf16 NHWC
// EPI 5: bf16 NHWC (Cout-wide, ORI1)    | EPI 6: fused mp_sum+clip -> f32 NCHW out (ORI2)
template<int KS, int ORI, int EPI>
__global__ __launch_bounds__(256) void convmfma(
        const __hip_bfloat16* __restrict__ xin,
        const __hip_bfloat16* __restrict__ wb,
        __hip_bfloat16* __restrict__ out_h,
        float* __restrict__ out_f,
        const float* __restrict__ xres,
        __hip_bfloat16* __restrict__ out_h2,
        const float* __restrict__ cvec,
        int Cin, int Cout) {
    constexpr int TAPS = KS * KS;
    constexpr int RRD = 8 + KS - 1;
    constexpr int CCD = 32 + KS - 1;
    constexpr int HLO = KS / 2;
    __shared__ __align__(16) __hip_bfloat16 Xl[RRD][CCD][40];
    __shared__ __align__(16) __hip_bfloat16 Wl[TAPS][64][40];

    int oc0 = blockIdx.x * 64;
    int spblk = blockIdx.y;
    int n = blockIdx.z;
    int r0 = spblk * 8;
    int lane = threadIdx.x & 63, wv = threadIdx.x >> 6;
    int l15 = lane & 15, kb = (lane >> 4) * 8;

    if (KS == 3) {
        if (threadIdx.x < RRD * 2 * 4) {
            int rr = threadIdx.x >> 3;
            int side = (threadIdx.x >> 2) & 1;
            int slot = threadIdx.x & 3;
            *(bf16x8*)&Xl[rr][side ? (CCD - 1) : 0][slot * 8] = bzero8();
        }
    }

    f32x4 acc[4][4];
    const f32x4 z4 = {0.f, 0.f, 0.f, 0.f};
#pragma unroll
    for (int a = 0; a < 4; a++)
#pragma unroll
        for (int b = 0; b < 4; b++) acc[a][b] = z4;

    int nch = Cin >> 5;
    for (int ch = 0; ch < nch; ++ch) {
        __syncthreads();
        for (int f = threadIdx.x; f < RRD * 128; f += 256) {
            int rr = f >> 7, rem = f & 127;
            int cc = rem >> 2, slot = rem & 3;
            int gr = r0 + rr - HLO;
            bf16x8 v = bzero8();
            if ((unsigned)gr < 32u)
                v = *(const bf16x8*)&xin[((size_t)n * 1024 + gr * 32 + cc) * Cin + ch * 32 + slot * 8];
            *(bf16x8*)&Xl[rr][cc + HLO][slot * 8] = v;
        }
        for (int f = threadIdx.x; f < TAPS * 256; f += 256) {
            int tap = f >> 8, rem = f & 255;
            int oc = rem >> 2, slot = rem & 3;
            bf16x8 v = *(const bf16x8*)&wb[((size_t)tap * Cout + oc0 + oc) * Cin + ch * 32 + slot * 8];
            *(bf16x8*)&Wl[tap][oc][slot * 8] = v;
        }
        __syncthreads();
#pragma unroll
        for (int tap = 0; tap < TAPS; ++tap) {
            int dy = tap / KS, dx = tap % KS;
            bf16x8 af[4], bfv[4];
#pragma unroll
            for (int of = 0; of < 4; of++)
                af[of] = *(const bf16x8*)&Wl[tap][of * 16 + l15][kb];
#pragma unroll
            for (int sf = 0; sf < 4; sf++) {
                int rr = 2 * wv + (sf >> 1) + dy;
                int cc2 = (sf & 1) * 16 + l15 + dx;
                bfv[sf] = *(const bf16x8*)&Xl[rr][cc2][kb];
            }
#pragma unroll
            for (int of = 0; of < 4; of++)
#pragma unroll
                for (int sf = 0; sf < 4; sf++) {
                    if (ORI == 1)
                        acc[of][sf] = __builtin_amdgcn_mfma_f32_16x16x32_bf16(af[of], bfv[sf], acc[of][sf], 0, 0, 0);
                    else
                        acc[of][sf] = __builtin_amdgcn_mfma_f32_16x16x32_bf16(bfv[sf], af[of], acc[of][sf], 0, 0, 0);
                }
        }
    }

#pragma unroll
    for (int of = 0; of < 4; of++)
#pragma unroll
        for (int sf = 0; sf < 4; sf++) {
            if constexpr (ORI == 1) {
                int row_l = 2 * wv + (sf >> 1);
                int col = (sf & 1) * 16 + l15;
                int sp = spblk * 256 + row_l * 32 + col;
                int ocb = oc0 + of * 16 + (lane >> 4) * 4;
                size_t a = ((size_t)n * 1024 + sp) * Cout + ocb;
                if constexpr (EPI == 1) {
                    float vv[4];
#pragma unroll
                    for (int r = 0; r < 4; r++) {
                        float t = acc[of][sf][r] * cvec[n * 256 + ocb + r];
                        vv[r] = t / (1.0f + __expf(-t)) * INV596;
                    }
                    store_bf4(&out_h[a], vv[0], vv[1], vv[2], vv[3]);
                } else if constexpr (EPI == 2) {
                    float4 xr = *(const float4*)&xres[a];
                    float v0 = WA * xr.x + WB * acc[of][sf][0];
                    float v1 = WA * xr.y + WB * acc[of][sf][1];
                    float v2 = WA * xr.z + WB * acc[of][sf][2];
                    float v3 = WA * xr.w + WB * acc[of][sf][3];
                    *(float4*)&out_f[a] = make_float4(v0, v1, v2, v3);
                    store_bf4(&out_h2[a], v0, v1, v2, v3);
                } else {    // EPI 5: bf16 NHWC
                    store_bf4(&out_h[a], acc[of][sf][0], acc[of][sf][1],
                              acc[of][sf][2], acc[of][sf][3]);
                }
            } else {
                // ORI2 D[sp][oc]: regs = 4 consecutive sp at fixed oc
                int oc = oc0 + of * 16 + l15;
                int spb = spblk * 256 + (2 * wv + (sf >> 1)) * 32 + (sf & 1) * 16 + (lane >> 4) * 4;
                if constexpr (EPI == 6) {
                    float vv[4];
#pragma unroll
                    for (int r = 0; r < 4; r++) {
                        float xr = xres[((size_t)n * 1024 + spb + r) * 256 + oc];
                        float vo = WA * xr + WB * acc[of][sf][r];
                        vv[r] = fminf(fmaxf(vo, -256.f), 256.f);
                    }
                    *(float4*)&out_f[((size_t)n * 256 + oc) * 1024 + spb] =
                        make_float4(vv[0], vv[1], vv[2], vv[3]);
                }
            }
        }
}

// ---------------- qkv norm: Q,K in place (+fold 1/8 into Q), V -> Vt[n][h][c][s] ----------------
__global__ __launch_bounds__(256) void qkvnorm2(__hip_bfloat16* __restrict__ qkv3,
                                                __hip_bfloat16* __restrict__ vt) {
    int t = blockIdx.y >> 2, h = blockIdx.y & 3;
    int n = blockIdx.z;
    int s = blockIdx.x * 256 + threadIdx.x;
    __hip_bfloat16* base = qkv3 + ((size_t)(n * 1024 + s)) * 768 + t * 256 + h * 64;
    float v[64];
    float ss = 0.f;
#pragma unroll
    for (int j = 0; j < 8; j++) {
        s16x8 b = *(const s16x8*)(base + j * 8);
#pragma unroll
        for (int e = 0; e < 8; e++) {
            float f = bfbits2f(b[e]);
            v[j * 8 + e] = f; ss += f * f;
        }
    }
    float inv = 1.0f / (EPSV + sqrtf(ss) * 0.125f);
    if (t == 0) inv *= 0.125f;           // fold 1/sqrt(CPH) into Q (exact pow2 in bf16)
    if (t < 2) {
#pragma unroll
        for (int j = 0; j < 8; j++) {
            __hip_bfloat16 tmp[8];
#pragma unroll
            for (int e = 0; e < 8; e++) tmp[e] = __float2bfloat16(v[j * 8 + e] * inv);
            *(s16x8*)(base + j * 8) = *(s16x8*)tmp;
        }
    } else {
#pragma unroll
        for (int c = 0; c < 64; c++)
            vt[((size_t)((n * 4 + h) * 64 + c)) * 1024 + s] = __float2bfloat16(v[c] * inv);
    }
}

// ---------------- MFMA flash attention ----------------
// grid (8 qtiles, 4 heads, 32 n), 256 thr (4 waves x 32 q). KBLK=64.
// S^T = mfma(K, Q); P^T bf16 -> per-wave LDS [q][k]; O = mfma(P, V^T).
__global__ __launch_bounds__(256) void attn_mfma(const __hip_bfloat16* __restrict__ qkv3,
                                                 const __hip_bfloat16* __restrict__ vt,
                                                 __hip_bfloat16* __restrict__ outp) {
    int qt = blockIdx.x, h = blockIdx.y, n = blockIdx.z;
    __shared__ __align__(16) __hip_bfloat16 Qs[128][72];
    __shared__ __align__(16) __hip_bfloat16 Ks[64][72];
    __shared__ __align__(16) __hip_bfloat16 Vs[64][72];   // V^T: [c][k]
    __shared__ __align__(16) __hip_bfloat16 Ps[4][32][72];
    int tid = threadIdx.x;
    int lane = tid & 63, wv = tid >> 6;
    int l15 = lane & 15, g = lane >> 4;

#pragma unroll
    for (int i = 0; i < 4; i++) {
        int f = tid + i * 256;
        int row = f >> 3, slot = f & 7;
        *(bf16x8*)&Qs[row][slot * 8] =
            *(const bf16x8*)&qkv3[((size_t)(n * 1024 + qt * 128 + row)) * 768 + h * 64 + slot * 8];
    }
    f32x4 acc_o[2][4];
    const f32x4 z4 = {0.f, 0.f, 0.f, 0.f};
#pragma unroll
    for (int a = 0; a < 2; a++)
#pragma unroll
        for (int b = 0; b < 4; b++) acc_o[a][b] = z4;
    float m_run[2] = {-1e30f, -1e30f}, l_run[2] = {0.f, 0.f};
    __syncthreads();

    for (int kt = 0; kt < 16; kt++) {
#pragma unroll
        for (int i = 0; i < 2; i++) {
            int f = tid + i * 256;
            int row = f >> 3, slot = f & 7;
            *(bf16x8*)&Ks[row][slot * 8] =
                *(const bf16x8*)&qkv3[((size_t)(n * 1024 + kt * 64 + row)) * 768 + 256 + h * 64 + slot * 8];
            *(bf16x8*)&Vs[row][slot * 8] =
                *(const bf16x8*)&vt[((size_t)((n * 4 + h) * 64 + row)) * 1024 + kt * 64 + slot * 8];
        }
        __syncthreads();

        // S^T[k][q]
        f32x4 accs[4][2];
#pragma unroll
        for (int a = 0; a < 4; a++)
#pragma unroll
            for (int b = 0; b < 2; b++) accs[a][b] = z4;
#pragma unroll
        for (int cc = 0; cc < 2; cc++) {
            bf16x8 kf[4], qf[2];
#pragma unroll
            for (int mf = 0; mf < 4; mf++)
                kf[mf] = *(const bf16x8*)&Ks[mf * 16 + l15][cc * 32 + g * 8];
#pragma unroll
            for (int nf = 0; nf < 2; nf++)
                qf[nf] = *(const bf16x8*)&Qs[wv * 32 + nf * 16 + l15][cc * 32 + g * 8];
#pragma unroll
            for (int mf = 0; mf < 4; mf++)
#pragma unroll
                for (int nf = 0; nf < 2; nf++)
                    accs[mf][nf] = __builtin_amdgcn_mfma_f32_16x16x32_bf16(kf[mf], qf[nf], accs[mf][nf], 0, 0, 0);
        }

        // online softmax (per q = nf*16 + l15)
        float fsc[2];
#pragma unroll
        for (int nf = 0; nf < 2; nf++) {
            float tm = -1e30f;
#pragma unroll
            for (int mf = 0; mf < 4; mf++)
#pragma unroll
                for (int r = 0; r < 4; r++) tm = fmaxf(tm, accs[mf][nf][r]);
            tm = fmaxf(tm, __shfl_xor(tm, 16));
            tm = fmaxf(tm, __shfl_xor(tm, 32));
            float mnew = fmaxf(m_run[nf], tm);
            float fr = __expf(m_run[nf] - mnew);
            m_run[nf] = mnew;
            float rs = 0.f;
#pragma unroll
            for (int mf = 0; mf < 4; mf++) {
                float p0 = __expf(accs[mf][nf][0] - mnew);
                float p1 = __expf(accs[mf][nf][1] - mnew);
                float p2 = __expf(accs[mf][nf][2] - mnew);
                float p3 = __expf(accs[mf][nf][3] - mnew);
                rs += p0 + p1 + p2 + p3;
                store_bf4(&Ps[wv][nf * 16 + l15][mf * 16 + g * 4], p0, p1, p2, p3);
            }
            rs += __shfl_xor(rs, 16);
            rs += __shfl_xor(rs, 32);
            l_run[nf] = l_run[nf] * fr + rs;
            fsc[nf] = fr;
        }

        // rescale O (O q = mf2*16 + g*4 + r)
#pragma unroll
        for (int mf2 = 0; mf2 < 2; mf2++)
#pragma unroll
            for (int r = 0; r < 4; r++) {
                float fv = __shfl(fsc[mf2], g * 4 + r);
#pragma unroll
                for (int nf2 = 0; nf2 < 4; nf2++) acc_o[mf2][nf2][r] *= fv;
            }

        // O += P * V^T
#pragma unroll
        for (int kc = 0; kc < 2; kc++) {
            bf16x8 pf[2], vf[4];
#pragma unroll
            for (int mf2 = 0; mf2 < 2; mf2++)
                pf[mf2] = *(const bf16x8*)&Ps[wv][mf2 * 16 + l15][kc * 32 + g * 8];
#pragma unroll
            for (int nf2 = 0; nf2 < 4; nf2++)
                vf[nf2] = *(const bf16x8*)&Vs[nf2 * 16 + l15][kc * 32 + g * 8];
#pragma unroll
            for (int mf2 = 0; mf2 < 2; mf2++)
#pragma unroll
                for (int nf2 = 0; nf2 < 4; nf2++)
                    acc_o[mf2][nf2] = __builtin_amdgcn_mfma_f32_16x16x32_bf16(pf[mf2], vf[nf2], acc_o[mf2][nf2], 0, 0, 0);
        }
        __syncthreads();
    }

    // epilogue: O / l, bf16 NHWC [n][s][h*64+c]
#pragma unroll
    for (int mf2 = 0; mf2 < 2; mf2++) {
        float ilr = 1.0f / l_run[mf2];
#pragma unroll
        for (int r = 0; r < 4; r++) {
            float il = __shfl(ilr, g * 4 + r);
            int q = qt * 128 + wv * 32 + mf2 * 16 + g * 4 + r;
#pragma unroll
            for (int nf2 = 0; nf2 < 4; nf2++)
                outp[((size_t)(n * 1024 + q)) * 256 + h * 64 + nf2 * 16 + l15] =
                    __float2bfloat16(acc_o[mf2][nf2][r] * il);
        }
    }
}

extern "C" void kernel_launch(void* const* d_in, const int* in_sizes, int n_in,
                              void* d_out, int out_size, void* d_ws, size_t ws_size,
                              hipStream_t stream) {
    (void)in_sizes; (void)n_in; (void)out_size; (void)ws_size;
    const float* x        = (const float*)d_in[0];
    const float* emb      = (const float*)d_in[1];
    const float* w_res0   = (const float*)d_in[2];
    const float* w_emb    = (const float*)d_in[3];
    const float* w_res1   = (const float*)d_in[4];
    const float* w_qkv    = (const float*)d_in[5];
    const float* w_proj   = (const float*)d_in[6];
    const float* emb_gain = (const float*)d_in[7];
    float* out = (float*)d_out;

    // layout (~98.5 MB, proven-safe footprint):
    // [0,32M)  X fp32 NHWC (x_n -> x1, in-place; read by proj epilogue)
    // [32,48M) A1h bf16: silu(x_n) -> x1h -> attn-out
    // [48,96M) QKV3 bf16 [n][1024][768] (t-major: t*256+h*64+c)
    // [96M..)  weights; Vt (16MB) lives in d_out until the final store.
    const size_t MB = 1048576;
    char* wsb = (char*)d_ws;
    float* X             = (float*)wsb;
    __hip_bfloat16* A1h  = (__hip_bfloat16*)(wsb + 32 * MB);
    __hip_bfloat16* A2h  = (__hip_bfloat16*)(wsb + 48 * MB);
    __hip_bfloat16* QKV3 = A2h;
    __hip_bfloat16* Vt   = (__hip_bfloat16*)d_out;
    char* wp = wsb + 96 * MB;
    __hip_bfloat16* W0B = (__hip_bfloat16*)wp;              wp += 9 * 256 * 256 * 2;
    __hip_bfloat16* W1B = (__hip_bfloat16*)wp;              wp += 9 * 256 * 256 * 2;
    __hip_bfloat16* WQB = (__hip_bfloat16*)wp;              wp += 768 * 256 * 2;
    __hip_bfloat16* WPB = (__hip_bfloat16*)wp;              wp += 256 * 256 * 2;
    float* WEN          = (float*)wp;                       wp += 256 * 768 * 4;
    float* CC           = (float*)wp;

    wnorm3k<<<256, 256, 0, stream>>>(w_res0, W0B);
    wnorm3k<<<256, 256, 0, stream>>>(w_res1, W1B);
    wnorm1kq<<<768, 256, 0, stream>>>(w_qkv, WQB);
    wnorm1k<<<256, 256, 0, stream>>>(w_proj, WPB);
    wnorm_kernel<<<256, 256, 0, stream>>>(w_emb, WEN, 768, 0.036084392f, emb_gain);

    pixnorm2<<<dim3(4, 32), 256, 0, stream>>>(x, X, A1h);
    emb_kernel<<<32, 256, 0, stream>>>(emb, WEN, CC);

    // conv3 #1: silu(x_n) -> silu(y*c) [bf16 NHWC]
    convmfma<3, 1, 1><<<dim3(4, 4, 32), 256, 0, stream>>>(A1h, W0B, A2h, nullptr, nullptr, nullptr, CC, 256, 256);
    // conv3 #2: -> x1 = mp_sum(x_n, y3) [fp32 X + bf16 A1h]
    convmfma<3, 1, 2><<<dim3(4, 4, 32), 256, 0, stream>>>(A2h, W1B, nullptr, X, X, A1h, nullptr, 256, 256);
    // qkv 1x1: x1h -> QKV3 [bf16 NHWC, t-major channels]
    convmfma<1, 1, 5><<<dim3(12, 4, 32), 256, 0, stream>>>(A1h, WQB, QKV3, nullptr, nullptr, nullptr, nullptr, 256, 768);
    qkvnorm2<<<dim3(4, 12, 32), 256, 0, stream>>>(QKV3, Vt);
    attn_mfma<<<dim3(8, 4, 32), 256, 0, stream>>>(QKV3, Vt, A1h);     // A1h = attn out
    // proj 1x1 + fused mp_sum + clip -> out (f32 NCHW)
    convmfma<1, 2, 6><<<dim3(4, 4, 32), 256, 0, stream>>>(A1h, WPB, nullptr, out, X, nullptr, nullptr, 256, 256);
}

// Round 5
// 376.102 us; speedup vs baseline: 9.2057x; 1.0015x over previous
//
#include <hip/hip_runtime.h>
#include <hip/hip_bf16.h>
#include <math.h>

#define EPSV 1e-4f
#define WA 0.91914503f          // 0.7 / sqrt(0.58)
#define WB 0.39392215f          // 0.3 / sqrt(0.58)
#define INV596 1.6778523f       // 1/0.596

typedef __bf16 bf16x8 __attribute__((ext_vector_type(8)));
typedef short  s16x8  __attribute__((ext_vector_type(8)));
typedef float  f32x4  __attribute__((ext_vector_type(4)));

__device__ inline bf16x8 bzero8() { s16x8 z = 0; return __builtin_bit_cast(bf16x8, z); }

__device__ inline void store_bf4(__hip_bfloat16* p, float a, float b, float c, float d) {
    __hip_bfloat16 t[4];
    t[0] = __float2bfloat16(a); t[1] = __float2bfloat16(b);
    t[2] = __float2bfloat16(c); t[3] = __float2bfloat16(d);
    *(short4*)p = *(short4*)t;
}

__device__ inline float bfbits2f(short u) {
    return __uint_as_float(((unsigned)(unsigned short)u) << 16);
}

// ---------------- weight norm: 3x3 conv -> bf16 [tap][oc][ic] ----------------
__global__ void wnorm3k(const float* __restrict__ w, __hip_bfloat16* __restrict__ wb) {
    int oc = blockIdx.x;
    const float* row = w + (size_t)oc * 2304;
    float ss = 0.f;
    for (int i = threadIdx.x; i < 2304; i += 256) { float v = row[i]; ss += v * v; }
#pragma unroll
    for (int m = 32; m >= 1; m >>= 1) ss += __shfl_xor(ss, m);
    __shared__ float sdata[4];
    int wid = threadIdx.x >> 6, lane = threadIdx.x & 63;
    if (lane == 0) sdata[wid] = ss;
    __syncthreads();
    float tot = sdata[0] + sdata[1] + sdata[2] + sdata[3];
    float s = (1.0f / 48.0f) / (EPSV + sqrtf(tot) * (1.0f / 48.0f));
    for (int i = threadIdx.x; i < 2304; i += 256) {
        int ic = i / 9, tap = i - ic * 9;
        wb[((size_t)tap * 256 + oc) * 256 + ic] = __float2bfloat16(row[i] * s);
    }
}

// ---------------- weight norm: 1x1 conv -> bf16 [oc][ic] (plain) ----------------
__global__ void wnorm1k(const float* __restrict__ w, __hip_bfloat16* __restrict__ wb) {
    int oc = blockIdx.x;
    const float* row = w + (size_t)oc * 256;
    float v0 = row[threadIdx.x];
    float ss = v0 * v0;
#pragma unroll
    for (int m = 32; m >= 1; m >>= 1) ss += __shfl_xor(ss, m);
    __shared__ float sdata[4];
    int wid = threadIdx.x >> 6, lane = threadIdx.x & 63;
    if (lane == 0) sdata[wid] = ss;
    __syncthreads();
    float tot = sdata[0] + sdata[1] + sdata[2] + sdata[3];
    float s = 0.0625f / (EPSV + sqrtf(tot) * 0.0625f);
    wb[(size_t)oc * 256 + threadIdx.x] = __float2bfloat16(v0 * s);
}

// ---------------- weight norm: qkv 1x1, rows permuted (h,c,t)->(t,h,c) ----------------
__global__ void wnorm1kq(const float* __restrict__ w, __hip_bfloat16* __restrict__ wb) {
    int oc = blockIdx.x;                    // original row: h*192 + c*3 + t
    const float* row = w + (size_t)oc * 256;
    float v0 = row[threadIdx.x];
    float ss = v0 * v0;
#pragma unroll
    for (int m = 32; m >= 1; m >>= 1) ss += __shfl_xor(ss, m);
    __shared__ float sdata[4];
    int wid = threadIdx.x >> 6, lane = threadIdx.x & 63;
    if (lane == 0) sdata[wid] = ss;
    __syncthreads();
    float tot = sdata[0] + sdata[1] + sdata[2] + sdata[3];
    float s = 0.0625f / (EPSV + sqrtf(tot) * 0.0625f);
    int h = oc / 192, rem = oc - h * 192;
    int c = rem / 3, t = rem - c * 3;
    int newoc = t * 256 + h * 64 + c;
    wb[(size_t)newoc * 256 + threadIdx.x] = __float2bfloat16(v0 * s);
}

// ---------------- weight norm fp32 (emb) ----------------
__global__ void wnorm_kernel(const float* __restrict__ w, float* __restrict__ wn,
                             int L, float invsqrtL, const float* __restrict__ gain_ptr) {
    int r = blockIdx.x;
    const float* row = w + (size_t)r * L;
    float ss = 0.f;
    for (int i = threadIdx.x; i < L; i += 256) { float v = row[i]; ss += v * v; }
#pragma unroll
    for (int m = 32; m >= 1; m >>= 1) ss += __shfl_xor(ss, m);
    __shared__ float sdata[4];
    int wid = threadIdx.x >> 6, lane = threadIdx.x & 63;
    if (lane == 0) sdata[wid] = ss;
    __syncthreads();
    float tot = sdata[0] + sdata[1] + sdata[2] + sdata[3];
    float g = gain_ptr ? gain_ptr[0] : 1.0f;
    float s = g * invsqrtL / (EPSV + sqrtf(tot) * invsqrtL);
    float* outr = wn + (size_t)r * L;
    for (int i = threadIdx.x; i < L; i += 256) outr[i] = row[i] * s;
}

// ---------------- pixel norm: NCHW fp32 in -> NHWC fp32 xn + NHWC bf16 silu ----------------
__global__ void pixnorm2(const float* __restrict__ x, float* __restrict__ Xn,
                         __hip_bfloat16* __restrict__ Ah) {
    int n = blockIdx.y;
    int sp = blockIdx.x * 256 + threadIdx.x;
    const float* xb = x + (size_t)n * 262144 + sp;
    float ss = 0.f;
#pragma unroll 8
    for (int c = 0; c < 256; c++) { float v = xb[(size_t)c << 10]; ss += v * v; }
    float inv = 1.0f / (EPSV + sqrtf(ss) * 0.0625f);
    float* xo = Xn + ((size_t)n * 1024 + sp) * 256;
    __hip_bfloat16* ao = Ah + ((size_t)n * 1024 + sp) * 256;
#pragma unroll 8
    for (int c = 0; c < 256; c++) {
        float v = xb[(size_t)c << 10] * inv;
        xo[c] = v;
        float s = v / (1.0f + __expf(-v)) * INV596;
        ao[c] = __float2bfloat16(s);
    }
}

// ---------------- c = emb @ w_emb_n^T + 1 ----------------
__global__ void emb_kernel(const float* __restrict__ emb, const float* __restrict__ wn,
                           float* __restrict__ cvec) {
    int n = blockIdx.x;
    __shared__ float es[768];
    for (int i = threadIdx.x; i < 768; i += 256) es[i] = emb[n * 768 + i];
    __syncthreads();
    const float* wr = wn + (size_t)threadIdx.x * 768;
    float acc = 0.f;
    for (int k = 0; k < 768; k++) acc += es[k] * wr[k];
    cvec[n * 256 + threadIdx.x] = acc + 1.0f;
}

// ---------------- MFMA implicit-GEMM conv ----------------
// KS: 3 or 1. ORI 1: D[oc][sp]; ORI 2: D[sp][oc].
// EPI 1: silu(acc*c) -> bf16 NHWC       | EPI 2: mp_sum(xres,acc) -> f32+bf16 NHWC
// EPI 5: bf16 NHWC (Cout-wide, ORI1)    | EPI 6: fused mp_sum+clip -> f32 NCHW out (ORI2)
template<int KS, int ORI, int EPI>
__global__ __launch_bounds__(256) void convmfma(
        const __hip_bfloat16* __restrict__ xin,
        const __hip_bfloat16* __restrict__ wb,
        __hip_bfloat16* __restrict__ out_h,
        float* __restrict__ out_f,
        const float* __restrict__ xres,
        __hip_bfloat16* __restrict__ out_h2,
        const float* __restrict__ cvec,
        int Cin, int Cout) {
    constexpr int TAPS = KS * KS;
    constexpr int RRD = 8 + KS - 1;
    constexpr int CCD = 32 + KS - 1;
    constexpr int HLO = KS / 2;
    __shared__ __align__(16) __hip_bfloat16 Xl[RRD][CCD][40];
    __shared__ __align__(16) __hip_bfloat16 Wl[TAPS][64][40];

    int oc0 = blockIdx.x * 64;
    int spblk = blockIdx.y;
    int n = blockIdx.z;
    int r0 = spblk * 8;
    int lane = threadIdx.x & 63, wv = threadIdx.x >> 6;
    int l15 = lane & 15, kb = (lane >> 4) * 8;

    if (KS == 3) {
        if (threadIdx.x < RRD * 2 * 4) {
            int rr = threadIdx.x >> 3;
            int side = (threadIdx.x >> 2) & 1;
            int slot = threadIdx.x & 3;
            *(bf16x8*)&Xl[rr][side ? (CCD - 1) : 0][slot * 8] = bzero8();
        }
    }

    f32x4 acc[4][4];
    const f32x4 z4 = {0.f, 0.f, 0.f, 0.f};
#pragma unroll
    for (int a = 0; a < 4; a++)
#pragma unroll
        for (int b = 0; b < 4; b++) acc[a][b] = z4;

    int nch = Cin >> 5;
    for (int ch = 0; ch < nch; ++ch) {
        __syncthreads();
        for (int f = threadIdx.x; f < RRD * 128; f += 256) {
            int rr = f >> 7, rem = f & 127;
            int cc = rem >> 2, slot = rem & 3;
            int gr = r0 + rr - HLO;
            bf16x8 v = bzero8();
            if ((unsigned)gr < 32u)
                v = *(const bf16x8*)&xin[((size_t)n * 1024 + gr * 32 + cc) * Cin + ch * 32 + slot * 8];
            *(bf16x8*)&Xl[rr][cc + HLO][slot * 8] = v;
        }
        for (int f = threadIdx.x; f < TAPS * 256; f += 256) {
            int tap = f >> 8, rem = f & 255;
            int oc = rem >> 2, slot = rem & 3;
            bf16x8 v = *(const bf16x8*)&wb[((size_t)tap * Cout + oc0 + oc) * Cin + ch * 32 + slot * 8];
            *(bf16x8*)&Wl[tap][oc][slot * 8] = v;
        }
        __syncthreads();
#pragma unroll
        for (int tap = 0; tap < TAPS; ++tap) {
            int dy = tap / KS, dx = tap % KS;
            bf16x8 af[4], bfv[4];
#pragma unroll
            for (int of = 0; of < 4; of++)
                af[of] = *(const bf16x8*)&Wl[tap][of * 16 + l15][kb];
#pragma unroll
            for (int sf = 0; sf < 4; sf++) {
                int rr = 2 * wv + (sf >> 1) + dy;
                int cc2 = (sf & 1) * 16 + l15 + dx;
                bfv[sf] = *(const bf16x8*)&Xl[rr][cc2][kb];
            }
#pragma unroll
            for (int of = 0; of < 4; of++)
#pragma unroll
                for (int sf = 0; sf < 4; sf++) {
                    if (ORI == 1)
                        acc[of][sf] = __builtin_amdgcn_mfma_f32_16x16x32_bf16(af[of], bfv[sf], acc[of][sf], 0, 0, 0);
                    else
                        acc[of][sf] = __builtin_amdgcn_mfma_f32_16x16x32_bf16(bfv[sf], af[of], acc[of][sf], 0, 0, 0);
                }
        }
    }

#pragma unroll
    for (int of = 0; of < 4; of++)
#pragma unroll
        for (int sf = 0; sf < 4; sf++) {
            if constexpr (ORI == 1) {
                int row_l = 2 * wv + (sf >> 1);
                int col = (sf & 1) * 16 + l15;
                int sp = spblk * 256 + row_l * 32 + col;
                int ocb = oc0 + of * 16 + (lane >> 4) * 4;
                size_t a = ((size_t)n * 1024 + sp) * Cout + ocb;
                if constexpr (EPI == 1) {
                    float vv[4];
#pragma unroll
                    for (int r = 0; r < 4; r++) {
                        float t = acc[of][sf][r] * cvec[n * 256 + ocb + r];
                        vv[r] = t / (1.0f + __expf(-t)) * INV596;
                    }
                    store_bf4(&out_h[a], vv[0], vv[1], vv[2], vv[3]);
                } else if constexpr (EPI == 2) {
                    float4 xr = *(const float4*)&xres[a];
                    float v0 = WA * xr.x + WB * acc[of][sf][0];
                    float v1 = WA * xr.y + WB * acc[of][sf][1];
                    float v2 = WA * xr.z + WB * acc[of][sf][2];
                    float v3 = WA * xr.w + WB * acc[of][sf][3];
                    *(float4*)&out_f[a] = make_float4(v0, v1, v2, v3);
                    store_bf4(&out_h2[a], v0, v1, v2, v3);
                } else {    // EPI 5: bf16 NHWC
                    store_bf4(&out_h[a], acc[of][sf][0], acc[of][sf][1],
                              acc[of][sf][2], acc[of][sf][3]);
                }
            } else {
                // ORI2 D[sp][oc]: regs = 4 consecutive sp at fixed oc
                int oc = oc0 + of * 16 + l15;
                int spb = spblk * 256 + (2 * wv + (sf >> 1)) * 32 + (sf & 1) * 16 + (lane >> 4) * 4;
                if constexpr (EPI == 6) {
                    float vv[4];
#pragma unroll
                    for (int r = 0; r < 4; r++) {
                        float xr = xres[((size_t)n * 1024 + spb + r) * 256 + oc];
                        float vo = WA * xr + WB * acc[of][sf][r];
                        vv[r] = fminf(fmaxf(vo, -256.f), 256.f);
                    }
                    *(float4*)&out_f[((size_t)n * 256 + oc) * 1024 + spb] =
                        make_float4(vv[0], vv[1], vv[2], vv[3]);
                }
            }
        }
}

// ---------------- qkv norm: Q,K in place (Q gets 1/8*log2e), V -> Vt[n][h][c][s] ----------------
__global__ __launch_bounds__(256) void qkvnorm2(__hip_bfloat16* __restrict__ qkv3,
                                                __hip_bfloat16* __restrict__ vt) {
    int t = blockIdx.y >> 2, h = blockIdx.y & 3;
    int n = blockIdx.z;
    int s = blockIdx.x * 256 + threadIdx.x;
    __hip_bfloat16* base = qkv3 + ((size_t)(n * 1024 + s)) * 768 + t * 256 + h * 64;
    float v[64];
    float ss = 0.f;
#pragma unroll
    for (int j = 0; j < 8; j++) {
        s16x8 b = *(const s16x8*)(base + j * 8);
#pragma unroll
        for (int e = 0; e < 8; e++) {
            float f = bfbits2f(b[e]);
            v[j * 8 + e] = f; ss += f * f;
        }
    }
    float inv = 1.0f / (EPSV + sqrtf(ss) * 0.125f);
    if (t == 0) inv *= 0.18033688f;      // fold (1/sqrt(CPH)) * log2(e) into Q
    if (t < 2) {
#pragma unroll
        for (int j = 0; j < 8; j++) {
            __hip_bfloat16 tmp[8];
#pragma unroll
            for (int e = 0; e < 8; e++) tmp[e] = __float2bfloat16(v[j * 8 + e] * inv);
            *(s16x8*)(base + j * 8) = *(s16x8*)tmp;
        }
    } else {
#pragma unroll
        for (int c = 0; c < 64; c++)
            vt[((size_t)((n * 4 + h) * 64 + c)) * 1024 + s] = __float2bfloat16(v[c] * inv);
    }
}

// ---------------- MFMA flash attention, v2 ----------------
// grid (8 qtiles, 4 heads, 32 n), 256 thr (4 waves x 32 q). KBLK=64.
// Q in registers; K/V/P in XOR-swizzled LDS (pitch 64); bounded-logit softmax
// (|logit*log2e| <= 11.6) -> no max tracking, no rescale; exp2 domain.
__device__ inline int swz64(int row, int c8) { return row * 64 + ((c8 ^ (row & 7)) << 3); }

__global__ __launch_bounds__(256) void attn_mfma(const __hip_bfloat16* __restrict__ qkv3,
                                                 const __hip_bfloat16* __restrict__ vt,
                                                 __hip_bfloat16* __restrict__ outp) {
    int qt = blockIdx.x, h = blockIdx.y, n = blockIdx.z;
    __shared__ __align__(16) __hip_bfloat16 Ks[64 * 64];
    __shared__ __align__(16) __hip_bfloat16 Vs[64 * 64];      // V^T: [c][k]
    __shared__ __align__(16) __hip_bfloat16 Ps[4][32 * 64];   // per-wave P[q][k]
    int tid = threadIdx.x;
    int lane = tid & 63, wv = tid >> 6;
    int l15 = lane & 15, g = lane >> 4;

    // Q fragments in registers: qreg[nf][cc] covers rows wv*32+nf*16+l15, k = cc*32+g*8
    bf16x8 qreg[2][2];
#pragma unroll
    for (int nf = 0; nf < 2; nf++)
#pragma unroll
        for (int cc = 0; cc < 2; cc++)
            qreg[nf][cc] = *(const bf16x8*)&qkv3[
                ((size_t)(n * 1024 + qt * 128 + wv * 32 + nf * 16 + l15)) * 768 + h * 64 + cc * 32 + g * 8];

    f32x4 acc_o[2][4];
    const f32x4 z4 = {0.f, 0.f, 0.f, 0.f};
#pragma unroll
    for (int a = 0; a < 2; a++)
#pragma unroll
        for (int b = 0; b < 4; b++) acc_o[a][b] = z4;
    float l_run[2] = {0.f, 0.f};

    for (int kt = 0; kt < 16; kt++) {
#pragma unroll
        for (int i = 0; i < 2; i++) {
            int f = tid + i * 256;
            int row = f >> 3, slot = f & 7;
            int d = swz64(row, slot);
            *(bf16x8*)&Ks[d] =
                *(const bf16x8*)&qkv3[((size_t)(n * 1024 + kt * 64 + row)) * 768 + 256 + h * 64 + slot * 8];
            *(bf16x8*)&Vs[d] =
                *(const bf16x8*)&vt[((size_t)((n * 4 + h) * 64 + row)) * 1024 + kt * 64 + slot * 8];
        }
        __syncthreads();

        // S^T[k][q] = K·Q^T (log2 domain)
        f32x4 accs[4][2];
#pragma unroll
        for (int a = 0; a < 4; a++)
#pragma unroll
            for (int b = 0; b < 2; b++) accs[a][b] = z4;
#pragma unroll
        for (int cc = 0; cc < 2; cc++) {
            bf16x8 kf[4];
#pragma unroll
            for (int mf = 0; mf < 4; mf++) {
                int row = mf * 16 + l15;
                kf[mf] = *(const bf16x8*)&Ks[swz64(row, cc * 4 + g)];
            }
#pragma unroll
            for (int mf = 0; mf < 4; mf++)
#pragma unroll
                for (int nf = 0; nf < 2; nf++)
                    accs[mf][nf] = __builtin_amdgcn_mfma_f32_16x16x32_bf16(kf[mf], qreg[nf][cc], accs[mf][nf], 0, 0, 0);
        }

        // softmax accumulate (no max tracking): p = exp2(s), l += sum
#pragma unroll
        for (int nf = 0; nf < 2; nf++) {
            int q = nf * 16 + l15;
            float rs = 0.f;
#pragma unroll
            for (int mf = 0; mf < 4; mf++) {
                float p0 = __builtin_amdgcn_exp2f(accs[mf][nf][0]);
                float p1 = __builtin_amdgcn_exp2f(accs[mf][nf][1]);
                float p2 = __builtin_amdgcn_exp2f(accs[mf][nf][2]);
                float p3 = __builtin_amdgcn_exp2f(accs[mf][nf][3]);
                rs += (p0 + p1) + (p2 + p3);
                int elem = swz64(q, mf * 2 + (g >> 1)) + (g & 1) * 4;
                store_bf4(&Ps[wv][elem], p0, p1, p2, p3);
            }
            rs += __shfl_xor(rs, 16);
            rs += __shfl_xor(rs, 32);
            l_run[nf] += rs;
        }

        // O += P · V^T   (per-wave Ps: no barrier needed before reads)
#pragma unroll
        for (int kc = 0; kc < 2; kc++) {
            bf16x8 pf[2], vf[4];
#pragma unroll
            for (int mf2 = 0; mf2 < 2; mf2++) {
                int row = mf2 * 16 + l15;
                pf[mf2] = *(const bf16x8*)&Ps[wv][swz64(row, kc * 4 + g)];
            }
#pragma unroll
            for (int nf2 = 0; nf2 < 4; nf2++) {
                int row = nf2 * 16 + l15;
                vf[nf2] = *(const bf16x8*)&Vs[swz64(row, kc * 4 + g)];
            }
#pragma unroll
            for (int mf2 = 0; mf2 < 2; mf2++)
#pragma unroll
                for (int nf2 = 0; nf2 < 4; nf2++)
                    acc_o[mf2][nf2] = __builtin_amdgcn_mfma_f32_16x16x32_bf16(pf[mf2], vf[nf2], acc_o[mf2][nf2], 0, 0, 0);
        }
        __syncthreads();
    }

    // epilogue: O / l, bf16 NHWC [n][s][h*64+c]
#pragma unroll
    for (int mf2 = 0; mf2 < 2; mf2++) {
        float ilr = 1.0f / l_run[mf2];
#pragma unroll
        for (int r = 0; r < 4; r++) {
            float il = __shfl(ilr, g * 4 + r);
            int q = qt * 128 + wv * 32 + mf2 * 16 + g * 4 + r;
#pragma unroll
            for (int nf2 = 0; nf2 < 4; nf2++)
                outp[((size_t)(n * 1024 + q)) * 256 + h * 64 + nf2 * 16 + l15] =
                    __float2bfloat16(acc_o[mf2][nf2][r] * il);
        }
    }
}

extern "C" void kernel_launch(void* const* d_in, const int* in_sizes, int n_in,
                              void* d_out, int out_size, void* d_ws, size_t ws_size,
                              hipStream_t stream) {
    (void)in_sizes; (void)n_in; (void)out_size; (void)ws_size;
    const float* x        = (const float*)d_in[0];
    const float* emb      = (const float*)d_in[1];
    const float* w_res0   = (const float*)d_in[2];
    const float* w_emb    = (const float*)d_in[3];
    const float* w_res1   = (const float*)d_in[4];
    const float* w_qkv    = (const float*)d_in[5];
    const float* w_proj   = (const float*)d_in[6];
    const float* emb_gain = (const float*)d_in[7];
    float* out = (float*)d_out;

    // layout (~98.5 MB):
    // [0,32M)  X fp32 NHWC (x_n -> x1, in-place; read by proj epilogue)
    // [32,48M) A1h bf16: silu(x_n) -> x1h -> attn-out
    // [48,96M) QKV3 bf16 [n][1024][768] (t-major: t*256+h*64+c)
    // [96M..)  weights; Vt (16MB) lives in d_out until the final store.
    const size_t MB = 1048576;
    char* wsb = (char*)d_ws;
    float* X             = (float*)wsb;
    __hip_bfloat16* A1h  = (__hip_bfloat16*)(wsb + 32 * MB);
    __hip_bfloat16* A2h  = (__hip_bfloat16*)(wsb + 48 * MB);
    __hip_bfloat16* QKV3 = A2h;
    __hip_bfloat16* Vt   = (__hip_bfloat16*)d_out;
    char* wp = wsb + 96 * MB;
    __hip_bfloat16* W0B = (__hip_bfloat16*)wp;              wp += 9 * 256 * 256 * 2;
    __hip_bfloat16* W1B = (__hip_bfloat16*)wp;              wp += 9 * 256 * 256 * 2;
    __hip_bfloat16* WQB = (__hip_bfloat16*)wp;              wp += 768 * 256 * 2;
    __hip_bfloat16* WPB = (__hip_bfloat16*)wp;              wp += 256 * 256 * 2;
    float* WEN          = (float*)wp;                       wp += 256 * 768 * 4;
    float* CC           = (float*)wp;

    wnorm3k<<<256, 256, 0, stream>>>(w_res0, W0B);
    wnorm3k<<<256, 256, 0, stream>>>(w_res1, W1B);
    wnorm1kq<<<768, 256, 0, stream>>>(w_qkv, WQB);
    wnorm1k<<<256, 256, 0, stream>>>(w_proj, WPB);
    wnorm_kernel<<<256, 256, 0, stream>>>(w_emb, WEN, 768, 0.036084392f, emb_gain);

    pixnorm2<<<dim3(4, 32), 256, 0, stream>>>(x, X, A1h);
    emb_kernel<<<32, 256, 0, stream>>>(emb, WEN, CC);

    // conv3 #1: silu(x_n) -> silu(y*c) [bf16 NHWC]
    convmfma<3, 1, 1><<<dim3(4, 4, 32), 256, 0, stream>>>(A1h, W0B, A2h, nullptr, nullptr, nullptr, CC, 256, 256);
    // conv3 #2: -> x1 = mp_sum(x_n, y3) [fp32 X + bf16 A1h]
    convmfma<3, 1, 2><<<dim3(4, 4, 32), 256, 0, stream>>>(A2h, W1B, nullptr, X, X, A1h, nullptr, 256, 256);
    // qkv 1x1: x1h -> QKV3 [bf16 NHWC, t-major channels]
    convmfma<1, 1, 5><<<dim3(12, 4, 32), 256, 0, stream>>>(A1h, WQB, QKV3, nullptr, nullptr, nullptr, nullptr, 256, 768);
    qkvnorm2<<<dim3(4, 12, 32), 256, 0, stream>>>(QKV3, Vt);
    attn_mfma<<<dim3(8, 4, 32), 256, 0, stream>>>(QKV3, Vt, A1h);     // A1h = attn out
    // proj 1x1 + fused mp_sum + clip -> out (f32 NCHW)
    convmfma<1, 2, 6><<<dim3(4, 4, 32), 256, 0, stream>>>(A1h, WPB, nullptr, out, X, nullptr, nullptr, 256, 256);
}

// Round 6
// 300.499 us; speedup vs baseline: 11.5217x; 1.2516x over previous
//
#include <hip/hip_runtime.h>
#include <hip/hip_bf16.h>
#include <math.h>

#define EPSV 1e-4f
#define WA 0.91914503f          // 0.7 / sqrt(0.58)
#define WB 0.39392215f          // 0.3 / sqrt(0.58)
#define INV596 1.6778523f       // 1/0.596

typedef __bf16 bf16x8 __attribute__((ext_vector_type(8)));
typedef short  s16x8  __attribute__((ext_vector_type(8)));
typedef float  f32x4  __attribute__((ext_vector_type(4)));

__device__ inline bf16x8 bzero8() { s16x8 z = 0; return __builtin_bit_cast(bf16x8, z); }

__device__ inline void store_bf4(__hip_bfloat16* p, float a, float b, float c, float d) {
    __hip_bfloat16 t[4];
    t[0] = __float2bfloat16(a); t[1] = __float2bfloat16(b);
    t[2] = __float2bfloat16(c); t[3] = __float2bfloat16(d);
    *(short4*)p = *(short4*)t;
}

__device__ inline float bfbits2f(short u) {
    return __uint_as_float(((unsigned)(unsigned short)u) << 16);
}

// ---------------- weight norm: 3x3 conv -> bf16 [tap][oc][ic] ----------------
__global__ void wnorm3k(const float* __restrict__ w, __hip_bfloat16* __restrict__ wb) {
    int oc = blockIdx.x;
    const float* row = w + (size_t)oc * 2304;
    float ss = 0.f;
    for (int i = threadIdx.x; i < 2304; i += 256) { float v = row[i]; ss += v * v; }
#pragma unroll
    for (int m = 32; m >= 1; m >>= 1) ss += __shfl_xor(ss, m);
    __shared__ float sdata[4];
    int wid = threadIdx.x >> 6, lane = threadIdx.x & 63;
    if (lane == 0) sdata[wid] = ss;
    __syncthreads();
    float tot = sdata[0] + sdata[1] + sdata[2] + sdata[3];
    float s = (1.0f / 48.0f) / (EPSV + sqrtf(tot) * (1.0f / 48.0f));
    for (int i = threadIdx.x; i < 2304; i += 256) {
        int ic = i / 9, tap = i - ic * 9;
        wb[((size_t)tap * 256 + oc) * 256 + ic] = __float2bfloat16(row[i] * s);
    }
}

// ---------------- weight norm: 1x1 conv -> bf16 [oc][ic] (plain) ----------------
__global__ void wnorm1k(const float* __restrict__ w, __hip_bfloat16* __restrict__ wb) {
    int oc = blockIdx.x;
    const float* row = w + (size_t)oc * 256;
    float v0 = row[threadIdx.x];
    float ss = v0 * v0;
#pragma unroll
    for (int m = 32; m >= 1; m >>= 1) ss += __shfl_xor(ss, m);
    __shared__ float sdata[4];
    int wid = threadIdx.x >> 6, lane = threadIdx.x & 63;
    if (lane == 0) sdata[wid] = ss;
    __syncthreads();
    float tot = sdata[0] + sdata[1] + sdata[2] + sdata[3];
    float s = 0.0625f / (EPSV + sqrtf(tot) * 0.0625f);
    wb[(size_t)oc * 256 + threadIdx.x] = __float2bfloat16(v0 * s);
}

// ---------------- weight norm: qkv 1x1, rows permuted (h,c,t)->(t,h,c) ----------------
__global__ void wnorm1kq(const float* __restrict__ w, __hip_bfloat16* __restrict__ wb) {
    int oc = blockIdx.x;                    // original row: h*192 + c*3 + t
    const float* row = w + (size_t)oc * 256;
    float v0 = row[threadIdx.x];
    float ss = v0 * v0;
#pragma unroll
    for (int m = 32; m >= 1; m >>= 1) ss += __shfl_xor(ss, m);
    __shared__ float sdata[4];
    int wid = threadIdx.x >> 6, lane = threadIdx.x & 63;
    if (lane == 0) sdata[wid] = ss;
    __syncthreads();
    float tot = sdata[0] + sdata[1] + sdata[2] + sdata[3];
    float s = 0.0625f / (EPSV + sqrtf(tot) * 0.0625f);
    int h = oc / 192, rem = oc - h * 192;
    int c = rem / 3, t = rem - c * 3;
    int newoc = t * 256 + h * 64 + c;
    wb[(size_t)newoc * 256 + threadIdx.x] = __float2bfloat16(v0 * s);
}

// ---------------- weight norm fp32 (emb) ----------------
__global__ void wnorm_kernel(const float* __restrict__ w, float* __restrict__ wn,
                             int L, float invsqrtL, const float* __restrict__ gain_ptr) {
    int r = blockIdx.x;
    const float* row = w + (size_t)r * L;
    float ss = 0.f;
    for (int i = threadIdx.x; i < L; i += 256) { float v = row[i]; ss += v * v; }
#pragma unroll
    for (int m = 32; m >= 1; m >>= 1) ss += __shfl_xor(ss, m);
    __shared__ float sdata[4];
    int wid = threadIdx.x >> 6, lane = threadIdx.x & 63;
    if (lane == 0) sdata[wid] = ss;
    __syncthreads();
    float tot = sdata[0] + sdata[1] + sdata[2] + sdata[3];
    float g = gain_ptr ? gain_ptr[0] : 1.0f;
    float s = g * invsqrtL / (EPSV + sqrtf(tot) * invsqrtL);
    float* outr = wn + (size_t)r * L;
    for (int i = threadIdx.x; i < L; i += 256) outr[i] = row[i] * s;
}

// ---------------- pixel norm: NCHW fp32 in -> NHWC fp32 xn + NHWC bf16 silu ----------------
__global__ void pixnorm2(const float* __restrict__ x, float* __restrict__ Xn,
                         __hip_bfloat16* __restrict__ Ah) {
    int n = blockIdx.y;
    int sp = blockIdx.x * 256 + threadIdx.x;
    const float* xb = x + (size_t)n * 262144 + sp;
    float ss = 0.f;
#pragma unroll 8
    for (int c = 0; c < 256; c++) { float v = xb[(size_t)c << 10]; ss += v * v; }
    float inv = 1.0f / (EPSV + sqrtf(ss) * 0.0625f);
    float* xo = Xn + ((size_t)n * 1024 + sp) * 256;
    __hip_bfloat16* ao = Ah + ((size_t)n * 1024 + sp) * 256;
#pragma unroll 8
    for (int c = 0; c < 256; c++) {
        float v = xb[(size_t)c << 10] * inv;
        xo[c] = v;
        float s = v / (1.0f + __expf(-v)) * INV596;
        ao[c] = __float2bfloat16(s);
    }
}

// ---------------- c = emb @ w_emb_n^T + 1 ----------------
__global__ void emb_kernel(const float* __restrict__ emb, const float* __restrict__ wn,
                           float* __restrict__ cvec) {
    int n = blockIdx.x;
    __shared__ float es[768];
    for (int i = threadIdx.x; i < 768; i += 256) es[i] = emb[n * 768 + i];
    __syncthreads();
    const float* wr = wn + (size_t)threadIdx.x * 768;
    float acc = 0.f;
    for (int k = 0; k < 768; k++) acc += es[k] * wr[k];
    cvec[n * 256 + threadIdx.x] = acc + 1.0f;
}

// ---------------- MFMA implicit-GEMM conv (T14 double-buffered, T1 swizzled) ----------------
// KS: 3 or 1. ORI 1: D[oc][sp]; ORI 2: D[sp][oc].
// EPI 1: silu(acc*c) -> bf16 NHWC       | EPI 2: mp_sum(xres,acc) -> f32+bf16 NHWC
// EPI 5: bf16 NHWC (Cout-wide, ORI1)    | EPI 6: fused mp_sum+clip -> f32 NCHW out (ORI2)
template<int KS, int ORI, int EPI, int GX>
__global__ __launch_bounds__(256) void convmfma(
        const __hip_bfloat16* __restrict__ xin,
        const __hip_bfloat16* __restrict__ wb,
        __hip_bfloat16* __restrict__ out_h,
        float* __restrict__ out_f,
        const float* __restrict__ xres,
        __hip_bfloat16* __restrict__ out_h2,
        const float* __restrict__ cvec,
        int Cin, int Cout) {
    constexpr int TAPS = KS * KS;
    constexpr int RRD = 8 + KS - 1;
    constexpr int CCD = 32 + KS - 1;
    constexpr int HLO = KS / 2;
    constexpr int NX = (RRD * 128) / 256;        // 5 (KS=3) or 4 (KS=1), exact
    __shared__ __align__(16) __hip_bfloat16 Xl[RRD][CCD][40];
    __shared__ __align__(16) __hip_bfloat16 Wl[TAPS][64][40];

    // T1 XCD swizzle: GX oc-blocks share one (spblk,n) input tile -> same XCD.
    int lin = blockIdx.x + GX * (blockIdx.y + 4 * blockIdx.z);
    constexpr int NBLK = GX * 4 * 32;
    constexpr int CPX = NBLK >> 3;               // divisible by GX (GX in {4,12})
    int swz = (lin & 7) * CPX + (lin >> 3);
    int oc0 = (swz % GX) * 64;
    int W = swz / GX;
    int spblk = W & 3;
    int n = W >> 2;

    int tid = threadIdx.x;
    int r0 = spblk * 8;
    int lane = tid & 63, wv = tid >> 6;
    int l15 = lane & 15, kb = (lane >> 4) * 8;

    if (KS == 3) {
        if (tid < RRD * 2 * 4) {
            int rr = tid >> 3;
            int side = (tid >> 2) & 1;
            int slot = tid & 3;
            *(bf16x8*)&Xl[rr][side ? (CCD - 1) : 0][slot * 8] = bzero8();
        }
    }

    // T14 staging: issue-early into regs, ds_write-late.
    bf16x8 xp[NX];
    bf16x8 wpf[TAPS];
    auto loadX = [&](int ch) {
#pragma unroll
        for (int u = 0; u < NX; u++) {
            int f = tid + u * 256;
            int rr = f >> 7, rem = f & 127;
            int cc = rem >> 2, slot = rem & 3;
            int gr = r0 + rr - HLO;
            bf16x8 v = bzero8();
            if ((unsigned)gr < 32u)
                v = *(const bf16x8*)&xin[((size_t)n * 1024 + gr * 32 + cc) * Cin + ch * 32 + slot * 8];
            xp[u] = v;
        }
    };
    auto writeX = [&]() {
#pragma unroll
        for (int u = 0; u < NX; u++) {
            int f = tid + u * 256;
            int rr = f >> 7, rem = f & 127;
            int cc = rem >> 2, slot = rem & 3;
            *(bf16x8*)&Xl[rr][cc + HLO][slot * 8] = xp[u];
        }
    };
    auto loadW = [&](int ch) {
#pragma unroll
        for (int u = 0; u < TAPS; u++) {
            int f = tid + u * 256;
            int tap = f >> 8, rem = f & 255;
            int oc = rem >> 2, slot = rem & 3;
            wpf[u] = *(const bf16x8*)&wb[((size_t)tap * Cout + oc0 + oc) * Cin + ch * 32 + slot * 8];
        }
    };
    auto writeW = [&]() {
#pragma unroll
        for (int u = 0; u < TAPS; u++) {
            int f = tid + u * 256;
            int tap = f >> 8, rem = f & 255;
            int oc = rem >> 2, slot = rem & 3;
            *(bf16x8*)&Wl[tap][oc][slot * 8] = wpf[u];
        }
    };

    f32x4 acc[4][4];
    const f32x4 z4 = {0.f, 0.f, 0.f, 0.f};
#pragma unroll
    for (int a = 0; a < 4; a++)
#pragma unroll
        for (int b = 0; b < 4; b++) acc[a][b] = z4;

    int nch = Cin >> 5;
    loadX(0); loadW(0);
    writeX(); writeW();
    __syncthreads();

    for (int ch = 0; ch < nch; ++ch) {
        bool pf = (ch + 1 < nch);
        if (pf) { loadX(ch + 1); loadW(ch + 1); }     // issue; no wait needed yet
#pragma unroll
        for (int tap = 0; tap < TAPS; ++tap) {
            int dy = tap / KS, dx = tap % KS;
            bf16x8 af[4], bfv[4];
#pragma unroll
            for (int of = 0; of < 4; of++)
                af[of] = *(const bf16x8*)&Wl[tap][of * 16 + l15][kb];
#pragma unroll
            for (int sf = 0; sf < 4; sf++) {
                int rr = 2 * wv + (sf >> 1) + dy;
                int cc2 = (sf & 1) * 16 + l15 + dx;
                bfv[sf] = *(const bf16x8*)&Xl[rr][cc2][kb];
            }
#pragma unroll
            for (int of = 0; of < 4; of++)
#pragma unroll
                for (int sf = 0; sf < 4; sf++) {
                    if (ORI == 1)
                        acc[of][sf] = __builtin_amdgcn_mfma_f32_16x16x32_bf16(af[of], bfv[sf], acc[of][sf], 0, 0, 0);
                    else
                        acc[of][sf] = __builtin_amdgcn_mfma_f32_16x16x32_bf16(bfv[sf], af[of], acc[of][sf], 0, 0, 0);
                }
        }
        __syncthreads();
        if (pf) { writeX(); writeW(); __syncthreads(); }
    }

#pragma unroll
    for (int of = 0; of < 4; of++)
#pragma unroll
        for (int sf = 0; sf < 4; sf++) {
            if constexpr (ORI == 1) {
                int row_l = 2 * wv + (sf >> 1);
                int col = (sf & 1) * 16 + l15;
                int sp = spblk * 256 + row_l * 32 + col;
                int ocb = oc0 + of * 16 + (lane >> 4) * 4;
                size_t a = ((size_t)n * 1024 + sp) * Cout + ocb;
                if constexpr (EPI == 1) {
                    float vv[4];
#pragma unroll
                    for (int r = 0; r < 4; r++) {
                        float t = acc[of][sf][r] * cvec[n * 256 + ocb + r];
                        vv[r] = t / (1.0f + __expf(-t)) * INV596;
                    }
                    store_bf4(&out_h[a], vv[0], vv[1], vv[2], vv[3]);
                } else if constexpr (EPI == 2) {
                    float4 xr = *(const float4*)&xres[a];
                    float v0 = WA * xr.x + WB * acc[of][sf][0];
                    float v1 = WA * xr.y + WB * acc[of][sf][1];
                    float v2 = WA * xr.z + WB * acc[of][sf][2];
                    float v3 = WA * xr.w + WB * acc[of][sf][3];
                    *(float4*)&out_f[a] = make_float4(v0, v1, v2, v3);
                    store_bf4(&out_h2[a], v0, v1, v2, v3);
                } else {    // EPI 5: bf16 NHWC
                    store_bf4(&out_h[a], acc[of][sf][0], acc[of][sf][1],
                              acc[of][sf][2], acc[of][sf][3]);
                }
            } else {
                // ORI2 D[sp][oc]: regs = 4 consecutive sp at fixed oc
                int oc = oc0 + of * 16 + l15;
                int spb = spblk * 256 + (2 * wv + (sf >> 1)) * 32 + (sf & 1) * 16 + (lane >> 4) * 4;
                if constexpr (EPI == 6) {
                    float vv[4];
#pragma unroll
                    for (int r = 0; r < 4; r++) {
                        float xr = xres[((size_t)n * 1024 + spb + r) * 256 + oc];
                        float vo = WA * xr + WB * acc[of][sf][r];
                        vv[r] = fminf(fmaxf(vo, -256.f), 256.f);
                    }
                    *(float4*)&out_f[((size_t)n * 256 + oc) * 1024 + spb] =
                        make_float4(vv[0], vv[1], vv[2], vv[3]);
                }
            }
        }
}

// ---------------- qkv norm: Q,K in place (Q gets 1/8*log2e), V -> Vt[n][h][c][s] ----------------
__global__ __launch_bounds__(256) void qkvnorm2(__hip_bfloat16* __restrict__ qkv3,
                                                __hip_bfloat16* __restrict__ vt) {
    int t = blockIdx.y >> 2, h = blockIdx.y & 3;
    int n = blockIdx.z;
    int s = blockIdx.x * 256 + threadIdx.x;
    __hip_bfloat16* base = qkv3 + ((size_t)(n * 1024 + s)) * 768 + t * 256 + h * 64;
    float v[64];
    float ss = 0.f;
#pragma unroll
    for (int j = 0; j < 8; j++) {
        s16x8 b = *(const s16x8*)(base + j * 8);
#pragma unroll
        for (int e = 0; e < 8; e++) {
            float f = bfbits2f(b[e]);
            v[j * 8 + e] = f; ss += f * f;
        }
    }
    float inv = 1.0f / (EPSV + sqrtf(ss) * 0.125f);
    if (t == 0) inv *= 0.18033688f;      // fold (1/sqrt(CPH)) * log2(e) into Q
    if (t < 2) {
#pragma unroll
        for (int j = 0; j < 8; j++) {
            __hip_bfloat16 tmp[8];
#pragma unroll
            for (int e = 0; e < 8; e++) tmp[e] = __float2bfloat16(v[j * 8 + e] * inv);
            *(s16x8*)(base + j * 8) = *(s16x8*)tmp;
        }
    } else {
#pragma unroll
        for (int c = 0; c < 64; c++)
            vt[((size_t)((n * 4 + h) * 64 + c)) * 1024 + s] = __float2bfloat16(v[c] * inv);
    }
}

// ---------------- MFMA flash attention, v3: T1 swizzle + T14 double-buffer ----------------
// grid 1024 blocks (8 qt x 4 h x 32 n), 256 thr (4 waves x 32 q). KBLK=64.
__device__ inline int swz64(int row, int c8) { return row * 64 + ((c8 ^ (row & 7)) << 3); }

__global__ __launch_bounds__(256) void attn_mfma(const __hip_bfloat16* __restrict__ qkv3,
                                                 const __hip_bfloat16* __restrict__ vt,
                                                 __hip_bfloat16* __restrict__ outp) {
    // T1: the 8 qt-blocks sharing one (n,h) K/V stream land on one XCD.
    int lin = blockIdx.x + 8 * (blockIdx.y + 4 * blockIdx.z);
    int swz = (lin & 7) * 128 + (lin >> 3);
    int qt = swz & 7;
    int W = swz >> 3;
    int h = W & 3, n = W >> 2;

    __shared__ __align__(16) __hip_bfloat16 Ks[64 * 64];
    __shared__ __align__(16) __hip_bfloat16 Vs[64 * 64];      // V^T: [c][k]
    __shared__ __align__(16) __hip_bfloat16 Ps[4][32 * 64];   // per-wave P[q][k]
    int tid = threadIdx.x;
    int lane = tid & 63, wv = tid >> 6;
    int l15 = lane & 15, g = lane >> 4;

    // Q fragments in registers
    bf16x8 qreg[2][2];
#pragma unroll
    for (int nf = 0; nf < 2; nf++)
#pragma unroll
        for (int cc = 0; cc < 2; cc++)
            qreg[nf][cc] = *(const bf16x8*)&qkv3[
                ((size_t)(n * 1024 + qt * 128 + wv * 32 + nf * 16 + l15)) * 768 + h * 64 + cc * 32 + g * 8];

    // T14 K/V staging regs
    bf16x8 kp[2], vp[2];
    auto loadKV = [&](int kt) {
#pragma unroll
        for (int i = 0; i < 2; i++) {
            int f = tid + i * 256;
            int row = f >> 3, slot = f & 7;
            kp[i] = *(const bf16x8*)&qkv3[((size_t)(n * 1024 + kt * 64 + row)) * 768 + 256 + h * 64 + slot * 8];
            vp[i] = *(const bf16x8*)&vt[((size_t)((n * 4 + h) * 64 + row)) * 1024 + kt * 64 + slot * 8];
        }
    };
    auto writeKV = [&]() {
#pragma unroll
        for (int i = 0; i < 2; i++) {
            int f = tid + i * 256;
            int row = f >> 3, slot = f & 7;
            int d = swz64(row, slot);
            *(bf16x8*)&Ks[d] = kp[i];
            *(bf16x8*)&Vs[d] = vp[i];
        }
    };

    f32x4 acc_o[2][4];
    const f32x4 z4 = {0.f, 0.f, 0.f, 0.f};
#pragma unroll
    for (int a = 0; a < 2; a++)
#pragma unroll
        for (int b = 0; b < 4; b++) acc_o[a][b] = z4;
    float l_run[2] = {0.f, 0.f};

    loadKV(0); writeKV();
    __syncthreads();

    for (int kt = 0; kt < 16; kt++) {
        if (kt < 15) loadKV(kt + 1);     // issue next tile; latency hides under compute

        // S^T[k][q] = K·Q^T (log2 domain)
        f32x4 accs[4][2];
#pragma unroll
        for (int a = 0; a < 4; a++)
#pragma unroll
            for (int b = 0; b < 2; b++) accs[a][b] = z4;
#pragma unroll
        for (int cc = 0; cc < 2; cc++) {
            bf16x8 kf[4];
#pragma unroll
            for (int mf = 0; mf < 4; mf++) {
                int row = mf * 16 + l15;
                kf[mf] = *(const bf16x8*)&Ks[swz64(row, cc * 4 + g)];
            }
#pragma unroll
            for (int mf = 0; mf < 4; mf++)
#pragma unroll
                for (int nf = 0; nf < 2; nf++)
                    accs[mf][nf] = __builtin_amdgcn_mfma_f32_16x16x32_bf16(kf[mf], qreg[nf][cc], accs[mf][nf], 0, 0, 0);
        }

        // bounded-logit softmax: p = exp2(s), l += sum (no max tracking)
#pragma unroll
        for (int nf = 0; nf < 2; nf++) {
            int q = nf * 16 + l15;
            float rs = 0.f;
#pragma unroll
            for (int mf = 0; mf < 4; mf++) {
                float p0 = __builtin_amdgcn_exp2f(accs[mf][nf][0]);
                float p1 = __builtin_amdgcn_exp2f(accs[mf][nf][1]);
                float p2 = __builtin_amdgcn_exp2f(accs[mf][nf][2]);
                float p3 = __builtin_amdgcn_exp2f(accs[mf][nf][3]);
                rs += (p0 + p1) + (p2 + p3);
                int elem = swz64(q, mf * 2 + (g >> 1)) + (g & 1) * 4;
                store_bf4(&Ps[wv][elem], p0, p1, p2, p3);
            }
            rs += __shfl_xor(rs, 16);
            rs += __shfl_xor(rs, 32);
            l_run[nf] += rs;
        }

        // O += P · V^T   (per-wave Ps: same-wave RAW handled by lgkmcnt)
#pragma unroll
        for (int kc = 0; kc < 2; kc++) {
            bf16x8 pf[2], vf[4];
#pragma unroll
            for (int mf2 = 0; mf2 < 2; mf2++) {
                int row = mf2 * 16 + l15;
                pf[mf2] = *(const bf16x8*)&Ps[wv][swz64(row, kc * 4 + g)];
            }
#pragma unroll
            for (int nf2 = 0; nf2 < 4; nf2++) {
                int row = nf2 * 16 + l15;
                vf[nf2] = *(const bf16x8*)&Vs[swz64(row, kc * 4 + g)];
            }
#pragma unroll
            for (int mf2 = 0; mf2 < 2; mf2++)
#pragma unroll
                for (int nf2 = 0; nf2 < 4; nf2++)
                    acc_o[mf2][nf2] = __builtin_amdgcn_mfma_f32_16x16x32_bf16(pf[mf2], vf[nf2], acc_o[mf2][nf2], 0, 0, 0);
        }
        __syncthreads();
        if (kt < 15) { writeKV(); __syncthreads(); }
    }

    // epilogue: O / l, bf16 NHWC [n][s][h*64+c]
#pragma unroll
    for (int mf2 = 0; mf2 < 2; mf2++) {
        float ilr = 1.0f / l_run[mf2];
#pragma unroll
        for (int r = 0; r < 4; r++) {
            float il = __shfl(ilr, g * 4 + r);
            int q = qt * 128 + wv * 32 + mf2 * 16 + g * 4 + r;
#pragma unroll
            for (int nf2 = 0; nf2 < 4; nf2++)
                outp[((size_t)(n * 1024 + q)) * 256 + h * 64 + nf2 * 16 + l15] =
                    __float2bfloat16(acc_o[mf2][nf2][r] * il);
        }
    }
}

extern "C" void kernel_launch(void* const* d_in, const int* in_sizes, int n_in,
                              void* d_out, int out_size, void* d_ws, size_t ws_size,
                              hipStream_t stream) {
    (void)in_sizes; (void)n_in; (void)out_size; (void)ws_size;
    const float* x        = (const float*)d_in[0];
    const float* emb      = (const float*)d_in[1];
    const float* w_res0   = (const float*)d_in[2];
    const float* w_emb    = (const float*)d_in[3];
    const float* w_res1   = (const float*)d_in[4];
    const float* w_qkv    = (const float*)d_in[5];
    const float* w_proj   = (const float*)d_in[6];
    const float* emb_gain = (const float*)d_in[7];
    float* out = (float*)d_out;

    // layout (~98.5 MB):
    // [0,32M)  X fp32 NHWC (x_n -> x1, in-place; read by proj epilogue)
    // [32,48M) A1h bf16: silu(x_n) -> x1h -> attn-out
    // [48,96M) QKV3 bf16 [n][1024][768] (t-major: t*256+h*64+c)
    // [96M..)  weights; Vt (16MB) lives in d_out until the final store.
    const size_t MB = 1048576;
    char* wsb = (char*)d_ws;
    float* X             = (float*)wsb;
    __hip_bfloat16* A1h  = (__hip_bfloat16*)(wsb + 32 * MB);
    __hip_bfloat16* A2h  = (__hip_bfloat16*)(wsb + 48 * MB);
    __hip_bfloat16* QKV3 = A2h;
    __hip_bfloat16* Vt   = (__hip_bfloat16*)d_out;
    char* wp = wsb + 96 * MB;
    __hip_bfloat16* W0B = (__hip_bfloat16*)wp;              wp += 9 * 256 * 256 * 2;
    __hip_bfloat16* W1B = (__hip_bfloat16*)wp;              wp += 9 * 256 * 256 * 2;
    __hip_bfloat16* WQB = (__hip_bfloat16*)wp;              wp += 768 * 256 * 2;
    __hip_bfloat16* WPB = (__hip_bfloat16*)wp;              wp += 256 * 256 * 2;
    float* WEN          = (float*)wp;                       wp += 256 * 768 * 4;
    float* CC           = (float*)wp;

    wnorm3k<<<256, 256, 0, stream>>>(w_res0, W0B);
    wnorm3k<<<256, 256, 0, stream>>>(w_res1, W1B);
    wnorm1kq<<<768, 256, 0, stream>>>(w_qkv, WQB);
    wnorm1k<<<256, 256, 0, stream>>>(w_proj, WPB);
    wnorm_kernel<<<256, 256, 0, stream>>>(w_emb, WEN, 768, 0.036084392f, emb_gain);

    pixnorm2<<<dim3(4, 32), 256, 0, stream>>>(x, X, A1h);
    emb_kernel<<<32, 256, 0, stream>>>(emb, WEN, CC);

    // conv3 #1: silu(x_n) -> silu(y*c) [bf16 NHWC]
    convmfma<3, 1, 1, 4><<<dim3(4, 4, 32), 256, 0, stream>>>(A1h, W0B, A2h, nullptr, nullptr, nullptr, CC, 256, 256);
    // conv3 #2: -> x1 = mp_sum(x_n, y3) [fp32 X + bf16 A1h]
    convmfma<3, 1, 2, 4><<<dim3(4, 4, 32), 256, 0, stream>>>(A2h, W1B, nullptr, X, X, A1h, nullptr, 256, 256);
    // qkv 1x1: x1h -> QKV3 [bf16 NHWC, t-major channels]
    convmfma<1, 1, 5, 12><<<dim3(12, 4, 32), 256, 0, stream>>>(A1h, WQB, QKV3, nullptr, nullptr, nullptr, nullptr, 256, 768);
    qkvnorm2<<<dim3(4, 12, 32), 256, 0, stream>>>(QKV3, Vt);
    attn_mfma<<<dim3(8, 4, 32), 256, 0, stream>>>(QKV3, Vt, A1h);     // A1h = attn out
    // proj 1x1 + fused mp_sum + clip -> out (f32 NCHW)
    convmfma<1, 2, 6, 4><<<dim3(4, 4, 32), 256, 0, stream>>>(A1h, WPB, nullptr, out, X, nullptr, nullptr, 256, 256);
}

// Round 7
// 280.416 us; speedup vs baseline: 12.3469x; 1.0716x over previous
//
#include <hip/hip_runtime.h>
#include <hip/hip_bf16.h>
#include <math.h>

#define EPSV 1e-4f
#define WA 0.91914503f          // 0.7 / sqrt(0.58)
#define WB 0.39392215f          // 0.3 / sqrt(0.58)
#define INV596 1.6778523f       // 1/0.596

typedef __bf16 bf16x8 __attribute__((ext_vector_type(8)));
typedef short  s16x8  __attribute__((ext_vector_type(8)));
typedef float  f32x4  __attribute__((ext_vector_type(4)));

__device__ inline bf16x8 bzero8() { s16x8 z = 0; return __builtin_bit_cast(bf16x8, z); }

__device__ inline void store_bf4(__hip_bfloat16* p, float a, float b, float c, float d) {
    __hip_bfloat16 t[4];
    t[0] = __float2bfloat16(a); t[1] = __float2bfloat16(b);
    t[2] = __float2bfloat16(c); t[3] = __float2bfloat16(d);
    *(short4*)p = *(short4*)t;
}

__device__ inline float bfbits2f(short u) {
    return __uint_as_float(((unsigned)(unsigned short)u) << 16);
}

// ---------------- weight norm: 3x3 conv -> bf16 [tap][oc][ic] ----------------
__global__ void wnorm3k(const float* __restrict__ w, __hip_bfloat16* __restrict__ wb) {
    int oc = blockIdx.x;
    const float* row = w + (size_t)oc * 2304;
    float ss = 0.f;
    for (int i = threadIdx.x; i < 2304; i += 256) { float v = row[i]; ss += v * v; }
#pragma unroll
    for (int m = 32; m >= 1; m >>= 1) ss += __shfl_xor(ss, m);
    __shared__ float sdata[4];
    int wid = threadIdx.x >> 6, lane = threadIdx.x & 63;
    if (lane == 0) sdata[wid] = ss;
    __syncthreads();
    float tot = sdata[0] + sdata[1] + sdata[2] + sdata[3];
    float s = (1.0f / 48.0f) / (EPSV + sqrtf(tot) * (1.0f / 48.0f));
    for (int i = threadIdx.x; i < 2304; i += 256) {
        int ic = i / 9, tap = i - ic * 9;
        wb[((size_t)tap * 256 + oc) * 256 + ic] = __float2bfloat16(row[i] * s);
    }
}

// ---------------- weight norm: 1x1 conv -> bf16 [oc][ic] (plain) ----------------
__global__ void wnorm1k(const float* __restrict__ w, __hip_bfloat16* __restrict__ wb) {
    int oc = blockIdx.x;
    const float* row = w + (size_t)oc * 256;
    float v0 = row[threadIdx.x];
    float ss = v0 * v0;
#pragma unroll
    for (int m = 32; m >= 1; m >>= 1) ss += __shfl_xor(ss, m);
    __shared__ float sdata[4];
    int wid = threadIdx.x >> 6, lane = threadIdx.x & 63;
    if (lane == 0) sdata[wid] = ss;
    __syncthreads();
    float tot = sdata[0] + sdata[1] + sdata[2] + sdata[3];
    float s = 0.0625f / (EPSV + sqrtf(tot) * 0.0625f);
    wb[(size_t)oc * 256 + threadIdx.x] = __float2bfloat16(v0 * s);
}

// ---------------- weight norm: qkv 1x1, rows permuted (h,c,t)->(t,h,c) ----------------
__global__ void wnorm1kq(const float* __restrict__ w, __hip_bfloat16* __restrict__ wb) {
    int oc = blockIdx.x;                    // original row: h*192 + c*3 + t
    const float* row = w + (size_t)oc * 256;
    float v0 = row[threadIdx.x];
    float ss = v0 * v0;
#pragma unroll
    for (int m = 32; m >= 1; m >>= 1) ss += __shfl_xor(ss, m);
    __shared__ float sdata[4];
    int wid = threadIdx.x >> 6, lane = threadIdx.x & 63;
    if (lane == 0) sdata[wid] = ss;
    __syncthreads();
    float tot = sdata[0] + sdata[1] + sdata[2] + sdata[3];
    float s = 0.0625f / (EPSV + sqrtf(tot) * 0.0625f);
    int h = oc / 192, rem = oc - h * 192;
    int c = rem / 3, t = rem - c * 3;
    int newoc = t * 256 + h * 64 + c;
    wb[(size_t)newoc * 256 + threadIdx.x] = __float2bfloat16(v0 * s);
}

// ---------------- weight norm fp32 (emb) ----------------
__global__ void wnorm_kernel(const float* __restrict__ w, float* __restrict__ wn,
                             int L, float invsqrtL, const float* __restrict__ gain_ptr) {
    int r = blockIdx.x;
    const float* row = w + (size_t)r * L;
    float ss = 0.f;
    for (int i = threadIdx.x; i < L; i += 256) { float v = row[i]; ss += v * v; }
#pragma unroll
    for (int m = 32; m >= 1; m >>= 1) ss += __shfl_xor(ss, m);
    __shared__ float sdata[4];
    int wid = threadIdx.x >> 6, lane = threadIdx.x & 63;
    if (lane == 0) sdata[wid] = ss;
    __syncthreads();
    float tot = sdata[0] + sdata[1] + sdata[2] + sdata[3];
    float g = gain_ptr ? gain_ptr[0] : 1.0f;
    float s = g * invsqrtL / (EPSV + sqrtf(tot) * invsqrtL);
    float* outr = wn + (size_t)r * L;
    for (int i = threadIdx.x; i < L; i += 256) outr[i] = row[i] * s;
}

// ---------------- pixel norm v2: high-occupancy, single-read ----------------
// grid (32, 32) = 1024 blocks, 256 thr = 8 cgroups x 32 sp. x NCHW fp32 ->
// Xn NHWC fp32 + Ah NHWC bf16 silu. Each thread keeps its 32 channels in regs.
__global__ __launch_bounds__(256) void pixnorm2(const float* __restrict__ x,
        float* __restrict__ Xn, __hip_bfloat16* __restrict__ Ah) {
    int n = blockIdx.y;
    int sp = blockIdx.x * 32 + (threadIdx.x & 31);
    int cg = threadIdx.x >> 5;              // 0..7
    const float* xb = x + (size_t)n * 262144 + ((size_t)cg << 15) + sp;
    float v[32];
    float ss = 0.f;
#pragma unroll
    for (int i = 0; i < 32; i++) {
        v[i] = xb[(size_t)i << 10];
        ss += v[i] * v[i];
    }
    __shared__ float red[8][33];
    red[cg][threadIdx.x & 31] = ss;
    __syncthreads();
    float tot = 0.f;
#pragma unroll
    for (int j = 0; j < 8; j++) tot += red[j][threadIdx.x & 31];
    float inv = 1.0f / (EPSV + sqrtf(tot) * 0.0625f);
    float* xo = Xn + ((size_t)n * 1024 + sp) * 256 + cg * 32;
    __hip_bfloat16* ao = Ah + ((size_t)n * 1024 + sp) * 256 + cg * 32;
#pragma unroll
    for (int i = 0; i < 32; i += 4) {
        float a0 = v[i] * inv, a1 = v[i+1] * inv, a2 = v[i+2] * inv, a3 = v[i+3] * inv;
        *(float4*)&xo[i] = make_float4(a0, a1, a2, a3);
        float s0 = a0 / (1.0f + __expf(-a0)) * INV596;
        float s1 = a1 / (1.0f + __expf(-a1)) * INV596;
        float s2 = a2 / (1.0f + __expf(-a2)) * INV596;
        float s3 = a3 / (1.0f + __expf(-a3)) * INV596;
        store_bf4(&ao[i], s0, s1, s2, s3);
    }
}

// ---------------- c = emb @ w_emb_n^T + 1 ----------------
__global__ void emb_kernel(const float* __restrict__ emb, const float* __restrict__ wn,
                           float* __restrict__ cvec) {
    int n = blockIdx.x;
    __shared__ float es[768];
    for (int i = threadIdx.x; i < 768; i += 256) es[i] = emb[n * 768 + i];
    __syncthreads();
    const float* wr = wn + (size_t)threadIdx.x * 768;
    float acc = 0.f;
    for (int k = 0; k < 768; k++) acc += es[k] * wr[k];
    cvec[n * 256 + threadIdx.x] = acc + 1.0f;
}

// ---------------- MFMA implicit-GEMM conv (T14 double-buffered, T1 swizzled) ----------------
// KS: 3 or 1. ORI 1: D[oc][sp]; ORI 2: D[sp][oc].
// EPI 1: silu(acc*c) -> bf16 NHWC       | EPI 2: mp_sum(xres,acc) -> f32+bf16 NHWC
// EPI 5: bf16 NHWC (Cout-wide, ORI1)    | EPI 6: fused mp_sum+clip -> f32 NCHW out (ORI2)
template<int KS, int ORI, int EPI, int GX>
__global__ __launch_bounds__(256) void convmfma(
        const __hip_bfloat16* __restrict__ xin,
        const __hip_bfloat16* __restrict__ wb,
        __hip_bfloat16* __restrict__ out_h,
        float* __restrict__ out_f,
        const float* __restrict__ xres,
        __hip_bfloat16* __restrict__ out_h2,
        const float* __restrict__ cvec,
        int Cin, int Cout) {
    constexpr int TAPS = KS * KS;
    constexpr int RRD = 8 + KS - 1;
    constexpr int CCD = 32 + KS - 1;
    constexpr int HLO = KS / 2;
    constexpr int NX = (RRD * 128) / 256;        // 5 (KS=3) or 4 (KS=1), exact
    __shared__ __align__(16) __hip_bfloat16 Xl[RRD][CCD][40];
    __shared__ __align__(16) __hip_bfloat16 Wl[TAPS][64][40];

    // T1 XCD swizzle: GX oc-blocks share one (spblk,n) input tile -> same XCD.
    int lin = blockIdx.x + GX * (blockIdx.y + 4 * blockIdx.z);
    constexpr int NBLK = GX * 4 * 32;
    constexpr int CPX = NBLK >> 3;               // divisible by GX (GX in {4,12})
    int swz = (lin & 7) * CPX + (lin >> 3);
    int oc0 = (swz % GX) * 64;
    int W = swz / GX;
    int spblk = W & 3;
    int n = W >> 2;

    int tid = threadIdx.x;
    int r0 = spblk * 8;
    int lane = tid & 63, wv = tid >> 6;
    int l15 = lane & 15, kb = (lane >> 4) * 8;

    if (KS == 3) {
        if (tid < RRD * 2 * 4) {
            int rr = tid >> 3;
            int side = (tid >> 2) & 1;
            int slot = tid & 3;
            *(bf16x8*)&Xl[rr][side ? (CCD - 1) : 0][slot * 8] = bzero8();
        }
    }

    // T14 staging: issue-early into regs, ds_write-late.
    bf16x8 xp[NX];
    bf16x8 wpf[TAPS];
    auto loadX = [&](int ch) {
#pragma unroll
        for (int u = 0; u < NX; u++) {
            int f = tid + u * 256;
            int rr = f >> 7, rem = f & 127;
            int cc = rem >> 2, slot = rem & 3;
            int gr = r0 + rr - HLO;
            bf16x8 v = bzero8();
            if ((unsigned)gr < 32u)
                v = *(const bf16x8*)&xin[((size_t)n * 1024 + gr * 32 + cc) * Cin + ch * 32 + slot * 8];
            xp[u] = v;
        }
    };
    auto writeX = [&]() {
#pragma unroll
        for (int u = 0; u < NX; u++) {
            int f = tid + u * 256;
            int rr = f >> 7, rem = f & 127;
            int cc = rem >> 2, slot = rem & 3;
            *(bf16x8*)&Xl[rr][cc + HLO][slot * 8] = xp[u];
        }
    };
    auto loadW = [&](int ch) {
#pragma unroll
        for (int u = 0; u < TAPS; u++) {
            int f = tid + u * 256;
            int tap = f >> 8, rem = f & 255;
            int oc = rem >> 2, slot = rem & 3;
            wpf[u] = *(const bf16x8*)&wb[((size_t)tap * Cout + oc0 + oc) * Cin + ch * 32 + slot * 8];
        }
    };
    auto writeW = [&]() {
#pragma unroll
        for (int u = 0; u < TAPS; u++) {
            int f = tid + u * 256;
            int tap = f >> 8, rem = f & 255;
            int oc = rem >> 2, slot = rem & 3;
            *(bf16x8*)&Wl[tap][oc][slot * 8] = wpf[u];
        }
    };

    f32x4 acc[4][4];
    const f32x4 z4 = {0.f, 0.f, 0.f, 0.f};
#pragma unroll
    for (int a = 0; a < 4; a++)
#pragma unroll
        for (int b = 0; b < 4; b++) acc[a][b] = z4;

    int nch = Cin >> 5;
    loadX(0); loadW(0);
    writeX(); writeW();
    __syncthreads();

    for (int ch = 0; ch < nch; ++ch) {
        bool pf = (ch + 1 < nch);
        if (pf) { loadX(ch + 1); loadW(ch + 1); }     // issue; no wait needed yet
#pragma unroll
        for (int tap = 0; tap < TAPS; ++tap) {
            int dy = tap / KS, dx = tap % KS;
            bf16x8 af[4], bfv[4];
#pragma unroll
            for (int of = 0; of < 4; of++)
                af[of] = *(const bf16x8*)&Wl[tap][of * 16 + l15][kb];
#pragma unroll
            for (int sf = 0; sf < 4; sf++) {
                int rr = 2 * wv + (sf >> 1) + dy;
                int cc2 = (sf & 1) * 16 + l15 + dx;
                bfv[sf] = *(const bf16x8*)&Xl[rr][cc2][kb];
            }
#pragma unroll
            for (int of = 0; of < 4; of++)
#pragma unroll
                for (int sf = 0; sf < 4; sf++) {
                    if (ORI == 1)
                        acc[of][sf] = __builtin_amdgcn_mfma_f32_16x16x32_bf16(af[of], bfv[sf], acc[of][sf], 0, 0, 0);
                    else
                        acc[of][sf] = __builtin_amdgcn_mfma_f32_16x16x32_bf16(bfv[sf], af[of], acc[of][sf], 0, 0, 0);
                }
        }
        __syncthreads();
        if (pf) { writeX(); writeW(); __syncthreads(); }
    }

#pragma unroll
    for (int of = 0; of < 4; of++)
#pragma unroll
        for (int sf = 0; sf < 4; sf++) {
            if constexpr (ORI == 1) {
                int row_l = 2 * wv + (sf >> 1);
                int col = (sf & 1) * 16 + l15;
                int sp = spblk * 256 + row_l * 32 + col;
                int ocb = oc0 + of * 16 + (lane >> 4) * 4;
                size_t a = ((size_t)n * 1024 + sp) * Cout + ocb;
                if constexpr (EPI == 1) {
                    float vv[4];
#pragma unroll
                    for (int r = 0; r < 4; r++) {
                        float t = acc[of][sf][r] * cvec[n * 256 + ocb + r];
                        vv[r] = t / (1.0f + __expf(-t)) * INV596;
                    }
                    store_bf4(&out_h[a], vv[0], vv[1], vv[2], vv[3]);
                } else if constexpr (EPI == 2) {
                    float4 xr = *(const float4*)&xres[a];
                    float v0 = WA * xr.x + WB * acc[of][sf][0];
                    float v1 = WA * xr.y + WB * acc[of][sf][1];
                    float v2 = WA * xr.z + WB * acc[of][sf][2];
                    float v3 = WA * xr.w + WB * acc[of][sf][3];
                    *(float4*)&out_f[a] = make_float4(v0, v1, v2, v3);
                    store_bf4(&out_h2[a], v0, v1, v2, v3);
                } else {    // EPI 5: bf16 NHWC
                    store_bf4(&out_h[a], acc[of][sf][0], acc[of][sf][1],
                              acc[of][sf][2], acc[of][sf][3]);
                }
            } else {
                // ORI2 D[sp][oc]: regs = 4 consecutive sp at fixed oc
                int oc = oc0 + of * 16 + l15;
                int spb = spblk * 256 + (2 * wv + (sf >> 1)) * 32 + (sf & 1) * 16 + (lane >> 4) * 4;
                if constexpr (EPI == 6) {
                    float vv[4];
#pragma unroll
                    for (int r = 0; r < 4; r++) {
                        float xr = xres[((size_t)n * 1024 + spb + r) * 256 + oc];
                        float vo = WA * xr + WB * acc[of][sf][r];
                        vv[r] = fminf(fmaxf(vo, -256.f), 256.f);
                    }
                    *(float4*)&out_f[((size_t)n * 256 + oc) * 1024 + spb] =
                        make_float4(vv[0], vv[1], vv[2], vv[3]);
                }
            }
        }
}

// ---------------- qkv norm: Q,K in place (Q gets 1/8*log2e), V -> Vt[n][h][c][s] ----------------
__global__ __launch_bounds__(256) void qkvnorm2(__hip_bfloat16* __restrict__ qkv3,
                                                __hip_bfloat16* __restrict__ vt) {
    int t = blockIdx.y >> 2, h = blockIdx.y & 3;
    int n = blockIdx.z;
    int s = blockIdx.x * 256 + threadIdx.x;
    __hip_bfloat16* base = qkv3 + ((size_t)(n * 1024 + s)) * 768 + t * 256 + h * 64;
    float v[64];
    float ss = 0.f;
#pragma unroll
    for (int j = 0; j < 8; j++) {
        s16x8 b = *(const s16x8*)(base + j * 8);
#pragma unroll
        for (int e = 0; e < 8; e++) {
            float f = bfbits2f(b[e]);
            v[j * 8 + e] = f; ss += f * f;
        }
    }
    float inv = 1.0f / (EPSV + sqrtf(ss) * 0.125f);
    if (t == 0) inv *= 0.18033688f;      // fold (1/sqrt(CPH)) * log2(e) into Q
    if (t < 2) {
#pragma unroll
        for (int j = 0; j < 8; j++) {
            __hip_bfloat16 tmp[8];
#pragma unroll
            for (int e = 0; e < 8; e++) tmp[e] = __float2bfloat16(v[j * 8 + e] * inv);
            *(s16x8*)(base + j * 8) = *(s16x8*)tmp;
        }
    } else {
#pragma unroll
        for (int c = 0; c < 64; c++)
            vt[((size_t)((n * 4 + h) * 64 + c)) * 1024 + s] = __float2bfloat16(v[c] * inv);
    }
}

// ---------------- MFMA flash attention, v3: T1 swizzle + T14 double-buffer ----------------
// grid 1024 blocks (8 qt x 4 h x 32 n), 256 thr (4 waves x 32 q). KBLK=64.
__device__ inline int swz64(int row, int c8) { return row * 64 + ((c8 ^ (row & 7)) << 3); }

__global__ __launch_bounds__(256) void attn_mfma(const __hip_bfloat16* __restrict__ qkv3,
                                                 const __hip_bfloat16* __restrict__ vt,
                                                 __hip_bfloat16* __restrict__ outp) {
    // T1: the 8 qt-blocks sharing one (n,h) K/V stream land on one XCD.
    int lin = blockIdx.x + 8 * (blockIdx.y + 4 * blockIdx.z);
    int swz = (lin & 7) * 128 + (lin >> 3);
    int qt = swz & 7;
    int W = swz >> 3;
    int h = W & 3, n = W >> 2;

    __shared__ __align__(16) __hip_bfloat16 Ks[64 * 64];
    __shared__ __align__(16) __hip_bfloat16 Vs[64 * 64];      // V^T: [c][k]
    __shared__ __align__(16) __hip_bfloat16 Ps[4][32 * 64];   // per-wave P[q][k]
    int tid = threadIdx.x;
    int lane = tid & 63, wv = tid >> 6;
    int l15 = lane & 15, g = lane >> 4;

    // Q fragments in registers
    bf16x8 qreg[2][2];
#pragma unroll
    for (int nf = 0; nf < 2; nf++)
#pragma unroll
        for (int cc = 0; cc < 2; cc++)
            qreg[nf][cc] = *(const bf16x8*)&qkv3[
                ((size_t)(n * 1024 + qt * 128 + wv * 32 + nf * 16 + l15)) * 768 + h * 64 + cc * 32 + g * 8];

    // T14 K/V staging regs
    bf16x8 kp[2], vp[2];
    auto loadKV = [&](int kt) {
#pragma unroll
        for (int i = 0; i < 2; i++) {
            int f = tid + i * 256;
            int row = f >> 3, slot = f & 7;
            kp[i] = *(const bf16x8*)&qkv3[((size_t)(n * 1024 + kt * 64 + row)) * 768 + 256 + h * 64 + slot * 8];
            vp[i] = *(const bf16x8*)&vt[((size_t)((n * 4 + h) * 64 + row)) * 1024 + kt * 64 + slot * 8];
        }
    };
    auto writeKV = [&]() {
#pragma unroll
        for (int i = 0; i < 2; i++) {
            int f = tid + i * 256;
            int row = f >> 3, slot = f & 7;
            int d = swz64(row, slot);
            *(bf16x8*)&Ks[d] = kp[i];
            *(bf16x8*)&Vs[d] = vp[i];
        }
    };

    f32x4 acc_o[2][4];
    const f32x4 z4 = {0.f, 0.f, 0.f, 0.f};
#pragma unroll
    for (int a = 0; a < 2; a++)
#pragma unroll
        for (int b = 0; b < 4; b++) acc_o[a][b] = z4;
    float l_run[2] = {0.f, 0.f};

    loadKV(0); writeKV();
    __syncthreads();

    for (int kt = 0; kt < 16; kt++) {
        if (kt < 15) loadKV(kt + 1);     // issue next tile; latency hides under compute

        // S^T[k][q] = K·Q^T (log2 domain)
        f32x4 accs[4][2];
#pragma unroll
        for (int a = 0; a < 4; a++)
#pragma unroll
            for (int b = 0; b < 2; b++) accs[a][b] = z4;
#pragma unroll
        for (int cc = 0; cc < 2; cc++) {
            bf16x8 kf[4];
#pragma unroll
            for (int mf = 0; mf < 4; mf++) {
                int row = mf * 16 + l15;
                kf[mf] = *(const bf16x8*)&Ks[swz64(row, cc * 4 + g)];
            }
#pragma unroll
            for (int mf = 0; mf < 4; mf++)
#pragma unroll
                for (int nf = 0; nf < 2; nf++)
                    accs[mf][nf] = __builtin_amdgcn_mfma_f32_16x16x32_bf16(kf[mf], qreg[nf][cc], accs[mf][nf], 0, 0, 0);
        }

        // bounded-logit softmax: p = exp2(s), l += sum (no max tracking)
#pragma unroll
        for (int nf = 0; nf < 2; nf++) {
            int q = nf * 16 + l15;
            float rs = 0.f;
#pragma unroll
            for (int mf = 0; mf < 4; mf++) {
                float p0 = __builtin_amdgcn_exp2f(accs[mf][nf][0]);
                float p1 = __builtin_amdgcn_exp2f(accs[mf][nf][1]);
                float p2 = __builtin_amdgcn_exp2f(accs[mf][nf][2]);
                float p3 = __builtin_amdgcn_exp2f(accs[mf][nf][3]);
                rs += (p0 + p1) + (p2 + p3);
                int elem = swz64(q, mf * 2 + (g >> 1)) + (g & 1) * 4;
                store_bf4(&Ps[wv][elem], p0, p1, p2, p3);
            }
            rs += __shfl_xor(rs, 16);
            rs += __shfl_xor(rs, 32);
            l_run[nf] += rs;
        }

        // O += P · V^T   (per-wave Ps: same-wave RAW handled by lgkmcnt)
#pragma unroll
        for (int kc = 0; kc < 2; kc++) {
            bf16x8 pf[2], vf[4];
#pragma unroll
            for (int mf2 = 0; mf2 < 2; mf2++) {
                int row = mf2 * 16 + l15;
                pf[mf2] = *(const bf16x8*)&Ps[wv][swz64(row, kc * 4 + g)];
            }
#pragma unroll
            for (int nf2 = 0; nf2 < 4; nf2++) {
                int row = nf2 * 16 + l15;
                vf[nf2] = *(const bf16x8*)&Vs[swz64(row, kc * 4 + g)];
            }
#pragma unroll
            for (int mf2 = 0; mf2 < 2; mf2++)
#pragma unroll
                for (int nf2 = 0; nf2 < 4; nf2++)
                    acc_o[mf2][nf2] = __builtin_amdgcn_mfma_f32_16x16x32_bf16(pf[mf2], vf[nf2], acc_o[mf2][nf2], 0, 0, 0);
        }
        __syncthreads();
        if (kt < 15) { writeKV(); __syncthreads(); }
    }

    // epilogue: O / l, bf16 NHWC [n][s][h*64+c]
#pragma unroll
    for (int mf2 = 0; mf2 < 2; mf2++) {
        float ilr = 1.0f / l_run[mf2];
#pragma unroll
        for (int r = 0; r < 4; r++) {
            float il = __shfl(ilr, g * 4 + r);
            int q = qt * 128 + wv * 32 + mf2 * 16 + g * 4 + r;
#pragma unroll
            for (int nf2 = 0; nf2 < 4; nf2++)
                outp[((size_t)(n * 1024 + q)) * 256 + h * 64 + nf2 * 16 + l15] =
                    __float2bfloat16(acc_o[mf2][nf2][r] * il);
        }
    }
}

extern "C" void kernel_launch(void* const* d_in, const int* in_sizes, int n_in,
                              void* d_out, int out_size, void* d_ws, size_t ws_size,
                              hipStream_t stream) {
    (void)in_sizes; (void)n_in; (void)out_size; (void)ws_size;
    const float* x        = (const float*)d_in[0];
    const float* emb      = (const float*)d_in[1];
    const float* w_res0   = (const float*)d_in[2];
    const float* w_emb    = (const float*)d_in[3];
    const float* w_res1   = (const float*)d_in[4];
    const float* w_qkv    = (const float*)d_in[5];
    const float* w_proj   = (const float*)d_in[6];
    const float* emb_gain = (const float*)d_in[7];
    float* out = (float*)d_out;

    // layout (~98.5 MB):
    // [0,32M)  X fp32 NHWC (x_n -> x1, in-place; read by proj epilogue)
    // [32,48M) A1h bf16: silu(x_n) -> x1h -> attn-out
    // [48,96M) QKV3 bf16 [n][1024][768] (t-major: t*256+h*64+c)
    // [96M..)  weights; Vt (16MB) lives in d_out until the final store.
    const size_t MB = 1048576;
    char* wsb = (char*)d_ws;
    float* X             = (float*)wsb;
    __hip_bfloat16* A1h  = (__hip_bfloat16*)(wsb + 32 * MB);
    __hip_bfloat16* A2h  = (__hip_bfloat16*)(wsb + 48 * MB);
    __hip_bfloat16* QKV3 = A2h;
    __hip_bfloat16* Vt   = (__hip_bfloat16*)d_out;
    char* wp = wsb + 96 * MB;
    __hip_bfloat16* W0B = (__hip_bfloat16*)wp;              wp += 9 * 256 * 256 * 2;
    __hip_bfloat16* W1B = (__hip_bfloat16*)wp;              wp += 9 * 256 * 256 * 2;
    __hip_bfloat16* WQB = (__hip_bfloat16*)wp;              wp += 768 * 256 * 2;
    __hip_bfloat16* WPB = (__hip_bfloat16*)wp;              wp += 256 * 256 * 2;
    float* WEN          = (float*)wp;                       wp += 256 * 768 * 4;
    float* CC           = (float*)wp;

    wnorm3k<<<256, 256, 0, stream>>>(w_res0, W0B);
    wnorm3k<<<256, 256, 0, stream>>>(w_res1, W1B);
    wnorm1kq<<<768, 256, 0, stream>>>(w_qkv, WQB);
    wnorm1k<<<256, 256, 0, stream>>>(w_proj, WPB);
    wnorm_kernel<<<256, 256, 0, stream>>>(w_emb, WEN, 768, 0.036084392f, emb_gain);

    pixnorm2<<<dim3(32, 32), 256, 0, stream>>>(x, X, A1h);
    emb_kernel<<<32, 256, 0, stream>>>(emb, WEN, CC);

    // conv3 #1: silu(x_n) -> silu(y*c) [bf16 NHWC]
    convmfma<3, 1, 1, 4><<<dim3(4, 4, 32), 256, 0, stream>>>(A1h, W0B, A2h, nullptr, nullptr, nullptr, CC, 256, 256);
    // conv3 #2: -> x1 = mp_sum(x_n, y3) [fp32 X + bf16 A1h]
    convmfma<3, 1, 2, 4><<<dim3(4, 4, 32), 256, 0, stream>>>(A2h, W1B, nullptr, X, X, A1h, nullptr, 256, 256);
    // qkv 1x1: x1h -> QKV3 [bf16 NHWC, t-major channels]
    convmfma<1, 1, 5, 12><<<dim3(12, 4, 32), 256, 0, stream>>>(A1h, WQB, QKV3, nullptr, nullptr, nullptr, nullptr, 256, 768);
    qkvnorm2<<<dim3(4, 12, 32), 256, 0, stream>>>(QKV3, Vt);
    attn_mfma<<<dim3(8, 4, 32), 256, 0, stream>>>(QKV3, Vt, A1h);     // A1h = attn out
    // proj 1x1 + fused mp_sum + clip -> out (f32 NCHW)
    convmfma<1, 2, 6, 4><<<dim3(4, 4, 32), 256, 0, stream>>>(A1h, WPB, nullptr, out, X, nullptr, nullptr, 256, 256);
}